// Round 11
// baseline (515.784 us; speedup 1.0000x reference)
//
#include <hip/hip_runtime.h>

#define NCELL 100000
#define NGENE 8000
#define DIM   128
#define NE_CG 1500000
#define NE_GC 1500000
#define NE_CC 1000000
#define NE_GG 200000
#define SLOPE 0.05f
#define LN_EPS 1e-5f

typedef __attribute__((ext_vector_type(2))) _Float16 f16x2;
typedef __attribute__((ext_vector_type(8))) _Float16 f16x8;
typedef __attribute__((ext_vector_type(4))) float f32x4;

__device__ __forceinline__ unsigned short f2h(float x) {
    return __builtin_bit_cast(unsigned short, (_Float16)x);
}
__device__ __forceinline__ unsigned pack2h(float x, float y) {
    f16x2 h = { (_Float16)x, (_Float16)y };
    return __builtin_bit_cast(unsigned, h);
}
__device__ __forceinline__ f16x2 u2h2(unsigned u) {
    return __builtin_bit_cast(f16x2, u);
}

// ================= binned CSR build, fixed-capacity bins =================
struct RelP {
    const int* src; const int* dst; int n; int shift;
    int nbins; int N; int cap;
    int* deg; int* offg; int* bkt;
    int* bcur; unsigned* stg;
    int cblk0;   // first block id in fill region (pre_k)
    int sblk0;   // first block id in csr grid
};

// ---------------- merged pre-pass: fill (bins) | weight pack | f32->f16 conv ----------
// Also zeroes the sentinel row (row N) of all four feature buffers: gather's
// out-of-range slots index the sentinel row, making loads AND adds unconditional.
__global__ __launch_bounds__(256)
void pre_k(RelP r0, RelP r1, RelP r2, RelP r3, int packBase, int convBase, int convCB,
           const float* __restrict__ h_cell, unsigned short* __restrict__ hcb,
           const float* __restrict__ h_gene, unsigned short* __restrict__ hgb,
           unsigned short* __restrict__ hcb1, unsigned short* __restrict__ hgb1,
           int n2c, int n2g,
           const float* __restrict__ WAc, const float* __restrict__ WBc,
           unsigned short* __restrict__ Wpc,
           const float* __restrict__ WAg, const float* __restrict__ WBg,
           unsigned short* __restrict__ Wpg) {
    __shared__ int cnt[512];
    __shared__ int basem[512];
    int b = blockIdx.x;
    int tid = threadIdx.x;

    if (b >= convBase) {
        // ---- f32 -> f16 conversion (cell then gene) ----
        int cb = b - convBase;
        const float* in; unsigned short* out; int i, n2;
        if (cb < convCB) { in = h_cell; out = hcb; n2 = n2c; i = cb * 256 + tid; }
        else             { in = h_gene; out = hgb; n2 = n2g; i = (cb - convCB) * 256 + tid; }
        if (i < n2) {
            float2 v = ((const float2*)in)[i];
            ((unsigned*)out)[i] = pack2h(v.x, v.y);
        }
        if (cb == 0) {
            // zero the sentinel rows (row NCELL / NGENE) of all four feature buffers
            if (tid < 64)       ((unsigned*)hcb )[n2c + tid]       = 0;
            else if (tid < 128) ((unsigned*)hcb1)[n2c + tid - 64]  = 0;
            else if (tid < 192) ((unsigned*)hgb )[n2g + tid - 128] = 0;
            else                ((unsigned*)hgb1)[n2g + tid - 192] = 0;
        }
        return;
    }
    if (b >= packBase) {
        // ---- weight pack: [W1;W2] -> MFMA B-frag layout (f16), 4 sub-blocks/block ----
        int sub = (b - packBase) * 4 + (tid >> 6);   // 0..127 (= original blockIdx)
        int lane = tid & 63;
        const float *WA, *WB; unsigned short* Wp; int bb;
        if (sub < 64) { WA = WAc; WB = WBc; Wp = Wpc; bb = sub; }
        else          { WA = WAg; WB = WBg; Wp = Wpg; bb = sub - 64; }
        int t = bb >> 3, cc = bb & 7;
        int n = t * 16 + (lane & 15);
        int k0 = cc * 32 + (lane >> 4) * 8;
        #pragma unroll
        for (int j = 0; j < 8; ++j) {
            int k = k0 + j;
            float x = (k < 128) ? WA[k * 128 + n] : WB[(k - 128) * 128 + n];
            Wp[((size_t)(bb * 64 + lane)) * 8 + j] = f2h(x);
        }
        return;
    }

    // ---- bin fill (fixed-cap bins) ----
    RelP R = (b >= r3.cblk0) ? r3 : (b >= r2.cblk0) ? r2 : (b >= r1.cblk0) ? r1 : r0;
    int lb = b - R.cblk0;
    cnt[tid] = 0; cnt[tid + 256] = 0;
    __syncthreads();
    int base = lb * 4096;
    int bins[16]; int ranks[16]; unsigned pk[16];
    #pragma unroll
    for (int it = 0; it < 16; ++it) {
        int i = base + it * 256 + tid;
        bins[it] = -1;
        if (i < R.n) {
            int d = R.dst[i];
            int bn = d >> R.shift;
            int dl = d & ((1 << R.shift) - 1);
            bins[it] = bn;
            pk[it] = (unsigned)R.src[i] | ((unsigned)dl << 20);
            ranks[it] = atomicAdd(&cnt[bn], 1);
        }
    }
    __syncthreads();
    if (cnt[tid])       basem[tid]       = atomicAdd(&R.bcur[tid],       cnt[tid]);
    if (cnt[tid + 256]) basem[tid + 256] = atomicAdd(&R.bcur[tid + 256], cnt[tid + 256]);
    __syncthreads();
    #pragma unroll
    for (int it = 0; it < 16; ++it)
        if (bins[it] >= 0) {
            int r = basem[bins[it]] + ranks[it];
            if (r >= R.cap) r = R.cap - 1;           // paranoia clamp (stays in own bin)
            R.stg[(size_t)bins[it] * R.cap + r] = pk[it];
        }
}

// counting-sort per bin; scatter goes to LDS, final global write is coalesced.
__global__ __launch_bounds__(256)
void bin_csr4_k(RelP r0, RelP r1, RelP r2, RelP r3) {
    int b = blockIdx.x;
    RelP R = (b >= r3.sblk0) ? r3 : (b >= r2.sblk0) ? r2 : (b >= r1.sblk0) ? r1 : r0;
    int lb = b - R.sblk0;
    int tid = threadIdx.x;
    int ebase = lb * R.cap;
    int cnt = R.bcur[lb]; if (cnt > R.cap) cnt = R.cap;
    __shared__ int degm[256];
    __shared__ int sc[256];
    __shared__ int cur[256];
    __shared__ int bktl[4352];   // >= max cap (CAP_GC)
    degm[tid] = 0;
    __syncthreads();
    for (int i = tid; i < cnt; i += 256)
        atomicAdd(&degm[(R.stg[ebase + i] >> 20) & 255], 1);
    __syncthreads();
    int x = degm[tid];
    sc[tid] = x;
    __syncthreads();
    for (int ofs = 1; ofs < 256; ofs <<= 1) {
        int t = (tid >= ofs) ? sc[tid - ofs] : 0;
        __syncthreads();
        sc[tid] += t;
        __syncthreads();
    }
    int excl = sc[tid] - x;
    cur[tid] = excl;
    int node = (lb << R.shift) + tid;
    if (tid < (1 << R.shift) && node < R.N) { R.deg[node] = x; R.offg[node] = ebase + excl; }
    __syncthreads();
    for (int i = tid; i < cnt; i += 256) {
        unsigned p = R.stg[ebase + i];
        int dl = (p >> 20) & 255;
        int r = atomicAdd(&cur[dl], 1);
        bktl[r] = (int)(p & 0xFFFFFu);
    }
    __syncthreads();
    for (int i = tid; i < cnt; i += 256)
        R.bkt[ebase + i] = bktl[i];
}

// ---------------- fused vectorized gather: split per-relation loops -------------------
// r10 post-mortem: merged A/B loop made relation B (gg deg~25) ride along for all
// ~47 t-iters of relation A (cg deg~187) on gene nodes -> ~40 dead sentinel
// loads+adds per wave. Split loops cut total load instrs ~27%. Each loop keeps the
// proven shape: exec-masked index preload + FULL-EXEC __shfl (r1/r2), wave-uniform
// t-skip (r6: no register arrays -> no scratch), sentinel zero-row unconditional
// loads/adds (r10: +0.0 exact in fp16). aA/aB accumulate the same edges in the same
// order as the merged loop -> bit-identical numerics. Gene blocks FIRST (LJF).
__global__ __launch_bounds__(256)
void gather2_k(const unsigned short* __restrict__ hc, const unsigned short* __restrict__ hg,
               const int* __restrict__ off_gc, const int* __restrict__ deg_gc, const int* __restrict__ bkt_gc,
               const int* __restrict__ off_cc, const int* __restrict__ deg_cc, const int* __restrict__ bkt_cc,
               const int* __restrict__ off_cg, const int* __restrict__ deg_cg, const int* __restrict__ bkt_cg,
               const int* __restrict__ off_gg, const int* __restrict__ deg_gg, const int* __restrict__ bkt_gg,
               unsigned short* __restrict__ Acat_c, unsigned short* __restrict__ Acat_g,
               int geneBlocks) {
    int wave = threadIdx.x >> 6, lane = threadIdx.x & 63;
    int g = lane >> 4, c = lane & 15;
    const unsigned short *hA, *hB;
    const int *offA, *degA, *bktA, *offB, *degB, *bktB;
    unsigned short* Aout; int node, N; int sentA, sentB;
    if ((int)blockIdx.x < geneBlocks) {
        node = blockIdx.x * 4 + wave; N = NGENE;
        hA = hc; offA = off_cg; degA = deg_cg; bktA = bkt_cg; sentA = NCELL;
        hB = hg; offB = off_gg; degB = deg_gg; bktB = bkt_gg; sentB = NGENE;
        Aout = Acat_g;
    } else {
        node = (blockIdx.x - geneBlocks) * 4 + wave; N = NCELL;
        hA = hg; offA = off_gc; degA = deg_gc; bktA = bkt_gc; sentA = NGENE;
        hB = hc; offB = off_cc; degB = deg_cc; bktB = bkt_cc; sentB = NCELL;
        Aout = Acat_c;
    }
    if (node >= N) return;

    int nA = degA[node], sA = offA[node];
    int nB = degB[node], sB = offB[node];

    f16x2 aA[4], aB[4];
    #pragma unroll
    for (int i = 0; i < 4; ++i) { aA[i] = (f16x2)(_Float16)0; aB[i] = (f16x2)(_Float16)0; }

    // ---- relation A ----
    for (int j0 = 0; j0 < nA; j0 += 32) {
        int jj = j0 + (lane & 31);
        int iv = sentA;
        if (lane < 32 && jj < nA) iv = bktA[sA + jj];   // exec-masked LOAD is fine
        int mxb = nA - j0;                               // wave-uniform
        #pragma unroll
        for (int t = 0; t < 8; ++t) {
            if (t * 4 < mxb) {          // wave-uniform skip: full exec at the shfl
                int j = t * 4 + g;      // j in 0..31 -> only lanes<32 sourced
                int sidx = __shfl(iv, j);
                uint4 v = *(const uint4*)(hA + (size_t)sidx * DIM + c * 8);
                aA[0] += u2h2(v.x); aA[1] += u2h2(v.y);
                aA[2] += u2h2(v.z); aA[3] += u2h2(v.w);
            }
        }
    }
    // ---- relation B ----
    for (int j0 = 0; j0 < nB; j0 += 32) {
        int jj = j0 + (lane & 31);
        int iv = sentB;
        if (lane < 32 && jj < nB) iv = bktB[sB + jj];
        int mxb = nB - j0;
        #pragma unroll
        for (int t = 0; t < 8; ++t) {
            if (t * 4 < mxb) {
                int j = t * 4 + g;
                int sidx = __shfl(iv, j);
                uint4 v = *(const uint4*)(hB + (size_t)sidx * DIM + c * 8);
                aB[0] += u2h2(v.x); aB[1] += u2h2(v.y);
                aB[2] += u2h2(v.z); aB[3] += u2h2(v.w);
            }
        }
    }

    // widen to f32, cross-group reduce, normalize, pack
    float fA[8], fB[8];
    #pragma unroll
    for (int i = 0; i < 4; ++i) {
        fA[2 * i]     = (float)aA[i][0]; fA[2 * i + 1] = (float)aA[i][1];
        fB[2 * i]     = (float)aB[i][0]; fB[2 * i + 1] = (float)aB[i][1];
    }
    #pragma unroll
    for (int i = 0; i < 8; ++i) {
        fA[i] += __shfl_xor(fA[i], 16); fA[i] += __shfl_xor(fA[i], 32);
        fB[i] += __shfl_xor(fB[i], 16); fB[i] += __shfl_xor(fB[i], 32);
    }
    float invA = 1.0f / fmaxf((float)nA, 1.0f);
    float invB = 1.0f / fmaxf((float)nB, 1.0f);
    uint4* outrow = (uint4*)(Aout + (size_t)node * 256);
    if (g == 0) {
        outrow[c] = make_uint4(pack2h(fA[0] * invA, fA[1] * invA), pack2h(fA[2] * invA, fA[3] * invA),
                               pack2h(fA[4] * invA, fA[5] * invA), pack2h(fA[6] * invA, fA[7] * invA));
    } else if (g == 1) {
        outrow[16 + c] = make_uint4(pack2h(fB[0] * invB, fB[1] * invB), pack2h(fB[2] * invB, fB[3] * invB),
                                    pack2h(fB[4] * invB, fB[5] * invB), pack2h(fB[6] * invB, fB[7] * invB));
    }
}

// ---------------- fused MFMA GEMM (f16) + bias + LeakyReLU + LN (cell & gene) ------------
// W read directly from global (64KB, L2-resident).
#define GBM 128
__global__ __launch_bounds__(256, 4)
void gemm2_ln_k(const unsigned short* __restrict__ Acat_c, const unsigned short* __restrict__ Acat_g,
                const unsigned short* __restrict__ Wp_c, const unsigned short* __restrict__ Wp_g,
                const float* __restrict__ bias_c, const float* __restrict__ bias_g,
                const float* __restrict__ ls_c, const float* __restrict__ lb_c,
                const float* __restrict__ ls_g, const float* __restrict__ lb_g,
                unsigned short* __restrict__ outh_c, unsigned short* __restrict__ outh_g,
                float* __restrict__ outf_c, float* __restrict__ outf_g,
                int cellBlocks) {
    const unsigned short *A, *Wp; const float *bias, *lns, *lnb;
    unsigned short* outh; float* outf; int M, mb;
    if ((int)blockIdx.x < cellBlocks) {
        A = Acat_c; Wp = Wp_c; bias = bias_c; lns = ls_c; lnb = lb_c;
        outh = outh_c; outf = outf_c; M = NCELL; mb = blockIdx.x;
    } else {
        A = Acat_g; Wp = Wp_g; bias = bias_g; lns = ls_g; lnb = lb_g;
        outh = outh_g; outf = outf_g; M = NGENE; mb = blockIdx.x - cellBlocks;
    }
    int tid = threadIdx.x;
    int wave = tid >> 6, lane = tid & 63;
    int col0 = lane & 15;
    int kq = lane >> 4;
    int m_base = mb * GBM + wave * 32;

    f32x4 acc[2][8];
    #pragma unroll
    for (int mt = 0; mt < 2; ++mt)
        #pragma unroll
        for (int t = 0; t < 8; ++t) acc[mt][t] = (f32x4){0.f, 0.f, 0.f, 0.f};

    const unsigned short* Ar0 = A + (size_t)(m_base + col0) * 256 + kq * 8;
    const unsigned short* Ar1 = Ar0 + 16 * 256;
    #pragma unroll
    for (int cc = 0; cc < 8; ++cc) {
        f16x8 a0 = *(const f16x8*)(Ar0 + cc * 32);
        f16x8 a1 = *(const f16x8*)(Ar1 + cc * 32);
        #pragma unroll
        for (int t = 0; t < 8; ++t) {
            f16x8 b = *(const f16x8*)(Wp + ((t * 8 + cc) * 64 + lane) * 8);
            acc[0][t] = __builtin_amdgcn_mfma_f32_16x16x32_f16(a0, b, acc[0][t], 0, 0, 0);
            acc[1][t] = __builtin_amdgcn_mfma_f32_16x16x32_f16(a1, b, acc[1][t], 0, 0, 0);
        }
    }

    float bias_r[8], s_r[8], b_r[8];
    #pragma unroll
    for (int t = 0; t < 8; ++t) {
        int col = t * 16 + col0;
        bias_r[t] = bias[col]; s_r[t] = lns[col]; b_r[t] = lnb[col];
    }
    #pragma unroll
    for (int mt = 0; mt < 2; ++mt) {
        #pragma unroll
        for (int r = 0; r < 4; ++r) {
            int row = m_base + mt * 16 + kq * 4 + r;
            float v[8]; float sum = 0.f, sq = 0.f;
            #pragma unroll
            for (int t = 0; t < 8; ++t) {
                float x = acc[mt][t][r] + bias_r[t];
                x = (x >= 0.f) ? x : SLOPE * x;
                v[t] = x; sum += x; sq += x * x;
            }
            #pragma unroll
            for (int ofs = 1; ofs <= 8; ofs <<= 1) {
                sum += __shfl_xor(sum, ofs);
                sq  += __shfl_xor(sq, ofs);
            }
            float mu = sum * (1.0f / 128.0f);
            float var = sq * (1.0f / 128.0f) - mu * mu;
            float rstd = rsqrtf(var + LN_EPS);
            if (row < M) {
                if (outh) {
                    #pragma unroll
                    for (int t = 0; t < 8; ++t)
                        outh[(size_t)row * 128 + t * 16 + col0] =
                            f2h((v[t] - mu) * rstd * s_r[t] + b_r[t]);
                } else {
                    #pragma unroll
                    for (int t = 0; t < 8; ++t)
                        outf[(size_t)row * 128 + t * 16 + col0] =
                            (v[t] - mu) * rstd * s_r[t] + b_r[t];
                }
            }
        }
    }
}

extern "C" void kernel_launch(void* const* d_in, const int* in_sizes, int n_in,
                              void* d_out, int out_size, void* d_ws, size_t ws_size,
                              hipStream_t stream) {
    const float* h_cell = (const float*)d_in[0];
    const float* h_gene = (const float*)d_in[1];
    const int* src_cg = (const int*)d_in[2];
    const int* dst_cg = (const int*)d_in[3];
    const int* src_gc = (const int*)d_in[4];
    const int* dst_gc = (const int*)d_in[5];
    const int* src_cc = (const int*)d_in[6];
    const int* dst_cc = (const int*)d_in[7];
    const int* src_gg = (const int*)d_in[8];
    const int* dst_gg = (const int*)d_in[9];
    const float* W_cg = (const float*)d_in[10];
    const float* W_gc = (const float*)d_in[11];
    const float* W_cc = (const float*)d_in[12];
    const float* W_gg = (const float*)d_in[13];
    const float* b_cell = (const float*)d_in[14];
    const float* b_gene = (const float*)d_in[15];
    const float* ln_s_cell = (const float*)d_in[16];
    const float* ln_b_cell = (const float*)d_in[17];
    const float* ln_s_gene = (const float*)d_in[18];
    const float* ln_b_gene = (const float*)d_in[19];
    float* out = (float*)d_out;

    const int MPC = ((NCELL + GBM - 1) / GBM) * GBM;
    const int MPG = ((NGENE + GBM - 1) / GBM) * GBM;
    const int NB_C = (NCELL + 255) / 256;   // 391 bins (shift 8)
    const int NB_G = (NGENE + 15) / 16;     // 500 bins (shift 4)
    // fixed bin capacities: mean + >8 sigma (Poisson)
    const int CAP_GC = 4352;   // mean 3836
    const int CAP_CC = 3072;   // mean 2558
    const int CAP_CG = 3584;   // mean 3000
    const int CAP_GG = 768;    // mean 400

    char* wsb = (char*)d_ws;
    size_t off = 0;
    auto alloc = [&](size_t bytes) -> char* {
        char* p = wsb + off;
        off = (off + bytes + 255) & ~(size_t)255;
        return p;
    };
    unsigned short* Acat_c = (unsigned short*)alloc((size_t)MPC * 256 * 2);
    unsigned short* Acat_g = (unsigned short*)alloc((size_t)MPG * 256 * 2);
    // feature buffers carry one extra SENTINEL row (row N, zeroed in pre_k)
    unsigned short* hcb0 = (unsigned short*)alloc((size_t)(NCELL + 1) * DIM * 2);
    unsigned short* hgb0 = (unsigned short*)alloc((size_t)(NGENE + 1) * DIM * 2);
    unsigned short* hcb1 = (unsigned short*)alloc((size_t)(NCELL + 1) * DIM * 2);
    unsigned short* hgb1 = (unsigned short*)alloc((size_t)(NGENE + 1) * DIM * 2);
    unsigned short* Wp_cell = (unsigned short*)alloc(65536);
    unsigned short* Wp_gene = (unsigned short*)alloc(65536);
    int ndeg = 2 * NCELL + 2 * NGENE;
    int* degs = (int*)alloc((size_t)ndeg * 4);
    int* deg_gc = degs;
    int* deg_cc = degs + NCELL;
    int* deg_cg = degs + 2 * NCELL;
    int* deg_gg = degs + 2 * NCELL + NGENE;
    int* offs = (int*)alloc((size_t)ndeg * 4);
    int* off_gc = offs;
    int* off_cc = offs + NCELL;
    int* off_cg = offs + 2 * NCELL;
    int* off_gg = offs + 2 * NCELL + NGENE;
    int* bkt_gc = (int*)alloc((size_t)NB_C * CAP_GC * 4);
    int* bkt_cc = (int*)alloc((size_t)NB_C * CAP_CC * 4);
    int* bkt_cg = (int*)alloc((size_t)NB_G * CAP_CG * 4);
    int* bkt_gg = (int*)alloc((size_t)NB_G * CAP_GG * 4);
    unsigned* stg_gc = (unsigned*)alloc((size_t)NB_C * CAP_GC * 4);
    unsigned* stg_cc = (unsigned*)alloc((size_t)NB_C * CAP_CC * 4);
    unsigned* stg_cg = (unsigned*)alloc((size_t)NB_G * CAP_CG * 4);
    unsigned* stg_gg = (unsigned*)alloc((size_t)NB_G * CAP_GG * 4);
    int* binmem = (int*)alloc(4 * 512 * 4);

    // ---- binned CSR build params ----
    hipMemsetAsync(binmem, 0, 4 * 512 * 4, stream);
    const int nbk_gc = (NE_GC + 4095) / 4096;
    const int nbk_cc = (NE_CC + 4095) / 4096;
    const int nbk_cg = (NE_CG + 4095) / 4096;
    const int nbk_gg = (NE_GG + 4095) / 4096;
    auto mkrel = [&](const int* s, const int* d, int n, int shift, int nbins, int N, int cap,
                     int* deg, int* offg, int* bkt, int* bm, unsigned* stg,
                     int cblk0, int sblk0) {
        RelP r;
        r.src = s; r.dst = d; r.n = n; r.shift = shift; r.nbins = nbins; r.N = N; r.cap = cap;
        r.deg = deg; r.offg = offg; r.bkt = bkt;
        r.bcur = bm; r.stg = stg;
        r.cblk0 = cblk0; r.sblk0 = sblk0;
        return r;
    };
    RelP r0 = mkrel(src_gc, dst_gc, NE_GC, 8, NB_C, NCELL, CAP_GC, deg_gc, off_gc, bkt_gc,
                    binmem + 0 * 512, stg_gc, 0, 0);
    RelP r1 = mkrel(src_cc, dst_cc, NE_CC, 8, NB_C, NCELL, CAP_CC, deg_cc, off_cc, bkt_cc,
                    binmem + 1 * 512, stg_cc, nbk_gc, NB_C);
    RelP r2 = mkrel(src_cg, dst_cg, NE_CG, 4, NB_G, NGENE, CAP_CG, deg_cg, off_cg, bkt_cg,
                    binmem + 2 * 512, stg_cg, nbk_gc + nbk_cc, 2 * NB_C);
    RelP r3 = mkrel(src_gg, dst_gg, NE_GG, 4, NB_G, NGENE, CAP_GG, deg_gg, off_gg, bkt_gg,
                    binmem + 3 * 512, stg_gg, nbk_gc + nbk_cc + nbk_cg, 2 * NB_C + NB_G);
    const int fillBlocks = nbk_gc + nbk_cc + nbk_cg + nbk_gg;
    const int csrBlocks = 2 * NB_C + 2 * NB_G;

    // ---- merged pre-pass: fill | pack (32 blocks) | conv (+ sentinel zeroing) ----
    const int n2c = NCELL * DIM / 2, n2g = NGENE * DIM / 2;
    const int convCB = (n2c + 255) / 256;
    const int convGB = (n2g + 255) / 256;
    const int packBase = fillBlocks;
    const int convBase = fillBlocks + 32;
    const int preBlocks = convBase + convCB + convGB;
    pre_k<<<preBlocks, 256, 0, stream>>>(r0, r1, r2, r3, packBase, convBase, convCB,
                                         h_cell, hcb0, h_gene, hgb0, hcb1, hgb1, n2c, n2g,
                                         W_gc, W_cc, Wp_cell, W_cg, W_gg, Wp_gene);
    bin_csr4_k<<<csrBlocks, 256, 0, stream>>>(r0, r1, r2, r3);

    // ---- two shared layers ----
    const int gatherCB = NCELL / 4;           // 25000
    const int gatherGB = (NGENE + 3) / 4;     // 2000 (scheduled FIRST: longest jobs)
    const int gemmCB = MPC / GBM;             // 782
    const int gemmGB = MPG / GBM;             // 63
    const unsigned short* hc = hcb0;
    const unsigned short* hg = hgb0;
    for (int layer = 0; layer < 2; ++layer) {
        int final_ = (layer == 1);
        gather2_k<<<gatherGB + gatherCB, 256, 0, stream>>>(
            hc, hg,
            off_gc, deg_gc, bkt_gc, off_cc, deg_cc, bkt_cc,
            off_cg, deg_cg, bkt_cg, off_gg, deg_gg, bkt_gg,
            Acat_c, Acat_g, gatherGB);
        gemm2_ln_k<<<gemmCB + gemmGB, 256, 0, stream>>>(
            Acat_c, Acat_g, Wp_cell, Wp_gene, b_cell, b_gene,
            ln_s_cell, ln_b_cell, ln_s_gene, ln_b_gene,
            final_ ? nullptr : hcb1, final_ ? nullptr : hgb1,
            final_ ? out : nullptr, final_ ? out + (size_t)NCELL * DIM : nullptr,
            gemmCB);
        hc = hcb1;
        hg = hgb1;
    }
}

// Round 12
// 486.662 us; speedup vs baseline: 1.0598x; 1.0598x over previous
//
#include <hip/hip_runtime.h>

#define NCELL 100000
#define NGENE 8000
#define DIM   128
#define NE_CG 1500000
#define NE_GC 1500000
#define NE_CC 1000000
#define NE_GG 200000
#define SLOPE 0.05f
#define LN_EPS 1e-5f

typedef __attribute__((ext_vector_type(2))) _Float16 f16x2;
typedef __attribute__((ext_vector_type(8))) _Float16 f16x8;
typedef __attribute__((ext_vector_type(4))) float f32x4;

__device__ __forceinline__ unsigned short f2h(float x) {
    return __builtin_bit_cast(unsigned short, (_Float16)x);
}
__device__ __forceinline__ unsigned pack2h(float x, float y) {
    f16x2 h = { (_Float16)x, (_Float16)y };
    return __builtin_bit_cast(unsigned, h);
}
__device__ __forceinline__ f16x2 u2h2(unsigned u) {
    return __builtin_bit_cast(f16x2, u);
}

// ================= binned CSR build, fixed-capacity bins =================
struct RelP {
    const int* src; const int* dst; int n; int shift;
    int nbins; int N; int cap;
    int* deg; int* offg; int* bkt;
    int* bcur; unsigned* stg;
    int cblk0;   // first block id in fill region (pre_k)
    int sblk0;   // first block id in csr grid
};

// ---------------- merged pre-pass: fill (bins) | weight pack | f32->f16 conv ----------
// Fill now sorts its 4096 edges by bin in LDS and writes stg segment-contiguously:
// destinations (bin*cap + basem + rank) and contents are BIT-IDENTICAL to the
// scattered version — only the write pattern changes (~8x fewer transactions).
// Also zeroes the sentinel row (row N) of all four feature buffers.
__global__ __launch_bounds__(256)
void pre_k(RelP r0, RelP r1, RelP r2, RelP r3, int packBase, int convBase, int convCB,
           const float* __restrict__ h_cell, unsigned short* __restrict__ hcb,
           const float* __restrict__ h_gene, unsigned short* __restrict__ hgb,
           unsigned short* __restrict__ hcb1, unsigned short* __restrict__ hgb1,
           int n2c, int n2g,
           const float* __restrict__ WAc, const float* __restrict__ WBc,
           unsigned short* __restrict__ Wpc,
           const float* __restrict__ WAg, const float* __restrict__ WBg,
           unsigned short* __restrict__ Wpg) {
    __shared__ int cnt[512];
    __shared__ int basem[512];
    __shared__ int scn[256];
    __shared__ int sscan[512];
    __shared__ unsigned spk[4096];
    __shared__ short sbin[4096];
    int b = blockIdx.x;
    int tid = threadIdx.x;

    if (b >= convBase) {
        // ---- f32 -> f16 conversion (cell then gene) ----
        int cb = b - convBase;
        const float* in; unsigned short* out; int i, n2;
        if (cb < convCB) { in = h_cell; out = hcb; n2 = n2c; i = cb * 256 + tid; }
        else             { in = h_gene; out = hgb; n2 = n2g; i = (cb - convCB) * 256 + tid; }
        if (i < n2) {
            float2 v = ((const float2*)in)[i];
            ((unsigned*)out)[i] = pack2h(v.x, v.y);
        }
        if (cb == 0) {
            // zero the sentinel rows (row NCELL / NGENE) of all four feature buffers
            if (tid < 64)       ((unsigned*)hcb )[n2c + tid]       = 0;
            else if (tid < 128) ((unsigned*)hcb1)[n2c + tid - 64]  = 0;
            else if (tid < 192) ((unsigned*)hgb )[n2g + tid - 128] = 0;
            else                ((unsigned*)hgb1)[n2g + tid - 192] = 0;
        }
        return;
    }
    if (b >= packBase) {
        // ---- weight pack: [W1;W2] -> MFMA B-frag layout (f16), 4 sub-blocks/block ----
        int sub = (b - packBase) * 4 + (tid >> 6);   // 0..127 (= original blockIdx)
        int lane = tid & 63;
        const float *WA, *WB; unsigned short* Wp; int bb;
        if (sub < 64) { WA = WAc; WB = WBc; Wp = Wpc; bb = sub; }
        else          { WA = WAg; WB = WBg; Wp = Wpg; bb = sub - 64; }
        int t = bb >> 3, cc = bb & 7;
        int n = t * 16 + (lane & 15);
        int k0 = cc * 32 + (lane >> 4) * 8;
        #pragma unroll
        for (int j = 0; j < 8; ++j) {
            int k = k0 + j;
            float x = (k < 128) ? WA[k * 128 + n] : WB[(k - 128) * 128 + n];
            Wp[((size_t)(bb * 64 + lane)) * 8 + j] = f2h(x);
        }
        return;
    }

    // ---- bin fill (fixed-cap bins), LDS-grouped coalesced staging writes ----
    RelP R = (b >= r3.cblk0) ? r3 : (b >= r2.cblk0) ? r2 : (b >= r1.cblk0) ? r1 : r0;
    int lb = b - R.cblk0;
    cnt[tid] = 0; cnt[tid + 256] = 0;
    __syncthreads();
    int base = lb * 4096;
    int bins[16]; int ranks[16]; unsigned pk[16];
    #pragma unroll
    for (int it = 0; it < 16; ++it) {
        int i = base + it * 256 + tid;
        bins[it] = -1;
        if (i < R.n) {
            int d = R.dst[i];
            int bn = d >> R.shift;
            int dl = d & ((1 << R.shift) - 1);
            bins[it] = bn;
            pk[it] = (unsigned)R.src[i] | ((unsigned)dl << 20);
            ranks[it] = atomicAdd(&cnt[bn], 1);
        }
    }
    __syncthreads();
    if (cnt[tid])       basem[tid]       = atomicAdd(&R.bcur[tid],       cnt[tid]);
    if (cnt[tid + 256]) basem[tid + 256] = atomicAdd(&R.bcur[tid + 256], cnt[tid + 256]);
    // block-local exclusive scan over the 512 bin counts (2 bins/thread)
    int c0 = cnt[2 * tid], c1 = cnt[2 * tid + 1];
    int ps = c0 + c1;
    scn[tid] = ps;
    __syncthreads();
    for (int ofs = 1; ofs < 256; ofs <<= 1) {
        int t = (tid >= ofs) ? scn[tid - ofs] : 0;
        __syncthreads();
        scn[tid] += t;
        __syncthreads();
    }
    int ex = scn[tid] - ps;
    sscan[2 * tid] = ex;
    sscan[2 * tid + 1] = ex + c0;
    __syncthreads();
    // place edges into block-sorted LDS order (by bin, rank order preserved)
    #pragma unroll
    for (int it = 0; it < 16; ++it)
        if (bins[it] >= 0) {
            int pos = sscan[bins[it]] + ranks[it];
            spk[pos] = pk[it];
            sbin[pos] = (short)bins[it];
        }
    __syncthreads();
    int total = sscan[511] + cnt[511];
    for (int idx = tid; idx < total; idx += 256) {
        int bn = sbin[idx];
        int rk = idx - sscan[bn];
        int r = basem[bn] + rk;
        if (r >= R.cap) r = R.cap - 1;           // paranoia clamp (stays in own bin)
        R.stg[(size_t)bn * R.cap + r] = spk[idx];
    }
}

// counting-sort per bin; scatter goes to LDS, final global write is coalesced.
__global__ __launch_bounds__(256)
void bin_csr4_k(RelP r0, RelP r1, RelP r2, RelP r3) {
    int b = blockIdx.x;
    RelP R = (b >= r3.sblk0) ? r3 : (b >= r2.sblk0) ? r2 : (b >= r1.sblk0) ? r1 : r0;
    int lb = b - R.sblk0;
    int tid = threadIdx.x;
    int ebase = lb * R.cap;
    int cnt = R.bcur[lb]; if (cnt > R.cap) cnt = R.cap;
    __shared__ int degm[256];
    __shared__ int sc[256];
    __shared__ int cur[256];
    __shared__ int bktl[4352];   // >= max cap (CAP_GC)
    degm[tid] = 0;
    __syncthreads();
    for (int i = tid; i < cnt; i += 256)
        atomicAdd(&degm[(R.stg[ebase + i] >> 20) & 255], 1);
    __syncthreads();
    int x = degm[tid];
    sc[tid] = x;
    __syncthreads();
    for (int ofs = 1; ofs < 256; ofs <<= 1) {
        int t = (tid >= ofs) ? sc[tid - ofs] : 0;
        __syncthreads();
        sc[tid] += t;
        __syncthreads();
    }
    int excl = sc[tid] - x;
    cur[tid] = excl;
    int node = (lb << R.shift) + tid;
    if (tid < (1 << R.shift) && node < R.N) { R.deg[node] = x; R.offg[node] = ebase + excl; }
    __syncthreads();
    for (int i = tid; i < cnt; i += 256) {
        unsigned p = R.stg[ebase + i];
        int dl = (p >> 20) & 255;
        int r = atomicAdd(&cur[dl], 1);
        bktl[r] = (int)(p & 0xFFFFFu);
    }
    __syncthreads();
    for (int i = tid; i < cnt; i += 256)
        R.bkt[ebase + i] = bktl[i];
}

// ---------------- fused vectorized gather: sentinel-row unconditional f16 pk-add ------
// r10 configuration (verified 117 us): MERGED A/B loop (max MLP: 2 independent loads
// per t-iter — r11 showed splitting loses 12% to exposed latency), sentinel zero-row
// unconditional loads/adds (+0.0 exact in fp16), wave-uniform t-skip (s_cbranch, no
// register arrays -> no scratch), gene blocks FIRST (LJF). Full-exec __shfl only.
__global__ __launch_bounds__(256)
void gather2_k(const unsigned short* __restrict__ hc, const unsigned short* __restrict__ hg,
               const int* __restrict__ off_gc, const int* __restrict__ deg_gc, const int* __restrict__ bkt_gc,
               const int* __restrict__ off_cc, const int* __restrict__ deg_cc, const int* __restrict__ bkt_cc,
               const int* __restrict__ off_cg, const int* __restrict__ deg_cg, const int* __restrict__ bkt_cg,
               const int* __restrict__ off_gg, const int* __restrict__ deg_gg, const int* __restrict__ bkt_gg,
               unsigned short* __restrict__ Acat_c, unsigned short* __restrict__ Acat_g,
               int geneBlocks) {
    int wave = threadIdx.x >> 6, lane = threadIdx.x & 63;
    int g = lane >> 4, c = lane & 15;
    const unsigned short *hA, *hB;
    const int *offA, *degA, *bktA, *offB, *degB, *bktB;
    unsigned short* Aout; int node, N; int sentA, sentB;
    if ((int)blockIdx.x < geneBlocks) {
        node = blockIdx.x * 4 + wave; N = NGENE;
        hA = hc; offA = off_cg; degA = deg_cg; bktA = bkt_cg; sentA = NCELL;
        hB = hg; offB = off_gg; degB = deg_gg; bktB = bkt_gg; sentB = NGENE;
        Aout = Acat_g;
    } else {
        node = (blockIdx.x - geneBlocks) * 4 + wave; N = NCELL;
        hA = hg; offA = off_gc; degA = deg_gc; bktA = bkt_gc; sentA = NGENE;
        hB = hc; offB = off_cc; degB = deg_cc; bktB = bkt_cc; sentB = NCELL;
        Aout = Acat_c;
    }
    if (node >= N) return;

    int nA = degA[node], sA = offA[node];
    int nB = degB[node], sB = offB[node];

    f16x2 aA[4], aB[4];
    #pragma unroll
    for (int i = 0; i < 4; ++i) { aA[i] = (f16x2)(_Float16)0; aB[i] = (f16x2)(_Float16)0; }
    int mx = (nA > nB) ? nA : nB;

    for (int j0 = 0; j0 < mx; j0 += 32) {
        // preload 32 indices per relation (wave-uniform bounds); OOB slots get the
        // sentinel zero-row index so downstream loads/adds need no guards.
        int l32 = lane & 31;
        int jj = j0 + l32;
        int iv;
        if (lane < 32) { iv = sentA; if (jj < nA) iv = bktA[sA + jj]; }
        else           { iv = sentB; if (jj < nB) iv = bktB[sB + jj]; }
        int mxb = mx - j0;            // wave-uniform remaining edge count
        #pragma unroll
        for (int t = 0; t < 8; ++t) {
            if (t * 4 < mxb) {        // wave-uniform skip: s_cbranch, full exec inside
                int j = t * 4 + g;
                int sidxA = __shfl(iv, j);
                int sidxB = __shfl(iv, 32 + j);
                uint4 vA = *(const uint4*)(hA + (size_t)sidxA * DIM + c * 8);
                uint4 vB = *(const uint4*)(hB + (size_t)sidxB * DIM + c * 8);
                aA[0] += u2h2(vA.x); aA[1] += u2h2(vA.y);
                aA[2] += u2h2(vA.z); aA[3] += u2h2(vA.w);
                aB[0] += u2h2(vB.x); aB[1] += u2h2(vB.y);
                aB[2] += u2h2(vB.z); aB[3] += u2h2(vB.w);
            }
        }
    }

    // widen to f32, cross-group reduce, normalize, pack
    float fA[8], fB[8];
    #pragma unroll
    for (int i = 0; i < 4; ++i) {
        fA[2 * i]     = (float)aA[i][0]; fA[2 * i + 1] = (float)aA[i][1];
        fB[2 * i]     = (float)aB[i][0]; fB[2 * i + 1] = (float)aB[i][1];
    }
    #pragma unroll
    for (int i = 0; i < 8; ++i) {
        fA[i] += __shfl_xor(fA[i], 16); fA[i] += __shfl_xor(fA[i], 32);
        fB[i] += __shfl_xor(fB[i], 16); fB[i] += __shfl_xor(fB[i], 32);
    }
    float invA = 1.0f / fmaxf((float)nA, 1.0f);
    float invB = 1.0f / fmaxf((float)nB, 1.0f);
    uint4* outrow = (uint4*)(Aout + (size_t)node * 256);
    if (g == 0) {
        outrow[c] = make_uint4(pack2h(fA[0] * invA, fA[1] * invA), pack2h(fA[2] * invA, fA[3] * invA),
                               pack2h(fA[4] * invA, fA[5] * invA), pack2h(fA[6] * invA, fA[7] * invA));
    } else if (g == 1) {
        outrow[16 + c] = make_uint4(pack2h(fB[0] * invB, fB[1] * invB), pack2h(fB[2] * invB, fB[3] * invB),
                                    pack2h(fB[4] * invB, fB[5] * invB), pack2h(fB[6] * invB, fB[7] * invB));
    }
}

// ---------------- fused MFMA GEMM (f16) + bias + LeakyReLU + LN (cell & gene) ------------
// W read directly from global (64KB, L2-resident).
#define GBM 128
__global__ __launch_bounds__(256, 4)
void gemm2_ln_k(const unsigned short* __restrict__ Acat_c, const unsigned short* __restrict__ Acat_g,
                const unsigned short* __restrict__ Wp_c, const unsigned short* __restrict__ Wp_g,
                const float* __restrict__ bias_c, const float* __restrict__ bias_g,
                const float* __restrict__ ls_c, const float* __restrict__ lb_c,
                const float* __restrict__ ls_g, const float* __restrict__ lb_g,
                unsigned short* __restrict__ outh_c, unsigned short* __restrict__ outh_g,
                float* __restrict__ outf_c, float* __restrict__ outf_g,
                int cellBlocks) {
    const unsigned short *A, *Wp; const float *bias, *lns, *lnb;
    unsigned short* outh; float* outf; int M, mb;
    if ((int)blockIdx.x < cellBlocks) {
        A = Acat_c; Wp = Wp_c; bias = bias_c; lns = ls_c; lnb = lb_c;
        outh = outh_c; outf = outf_c; M = NCELL; mb = blockIdx.x;
    } else {
        A = Acat_g; Wp = Wp_g; bias = bias_g; lns = ls_g; lnb = lb_g;
        outh = outh_g; outf = outf_g; M = NGENE; mb = blockIdx.x - cellBlocks;
    }
    int tid = threadIdx.x;
    int wave = tid >> 6, lane = tid & 63;
    int col0 = lane & 15;
    int kq = lane >> 4;
    int m_base = mb * GBM + wave * 32;

    f32x4 acc[2][8];
    #pragma unroll
    for (int mt = 0; mt < 2; ++mt)
        #pragma unroll
        for (int t = 0; t < 8; ++t) acc[mt][t] = (f32x4){0.f, 0.f, 0.f, 0.f};

    const unsigned short* Ar0 = A + (size_t)(m_base + col0) * 256 + kq * 8;
    const unsigned short* Ar1 = Ar0 + 16 * 256;
    #pragma unroll
    for (int cc = 0; cc < 8; ++cc) {
        f16x8 a0 = *(const f16x8*)(Ar0 + cc * 32);
        f16x8 a1 = *(const f16x8*)(Ar1 + cc * 32);
        #pragma unroll
        for (int t = 0; t < 8; ++t) {
            f16x8 b = *(const f16x8*)(Wp + ((t * 8 + cc) * 64 + lane) * 8);
            acc[0][t] = __builtin_amdgcn_mfma_f32_16x16x32_f16(a0, b, acc[0][t], 0, 0, 0);
            acc[1][t] = __builtin_amdgcn_mfma_f32_16x16x32_f16(a1, b, acc[1][t], 0, 0, 0);
        }
    }

    float bias_r[8], s_r[8], b_r[8];
    #pragma unroll
    for (int t = 0; t < 8; ++t) {
        int col = t * 16 + col0;
        bias_r[t] = bias[col]; s_r[t] = lns[col]; b_r[t] = lnb[col];
    }
    #pragma unroll
    for (int mt = 0; mt < 2; ++mt) {
        #pragma unroll
        for (int r = 0; r < 4; ++r) {
            int row = m_base + mt * 16 + kq * 4 + r;
            float v[8]; float sum = 0.f, sq = 0.f;
            #pragma unroll
            for (int t = 0; t < 8; ++t) {
                float x = acc[mt][t][r] + bias_r[t];
                x = (x >= 0.f) ? x : SLOPE * x;
                v[t] = x; sum += x; sq += x * x;
            }
            #pragma unroll
            for (int ofs = 1; ofs <= 8; ofs <<= 1) {
                sum += __shfl_xor(sum, ofs);
                sq  += __shfl_xor(sq, ofs);
            }
            float mu = sum * (1.0f / 128.0f);
            float var = sq * (1.0f / 128.0f) - mu * mu;
            float rstd = rsqrtf(var + LN_EPS);
            if (row < M) {
                if (outh) {
                    #pragma unroll
                    for (int t = 0; t < 8; ++t)
                        outh[(size_t)row * 128 + t * 16 + col0] =
                            f2h((v[t] - mu) * rstd * s_r[t] + b_r[t]);
                } else {
                    #pragma unroll
                    for (int t = 0; t < 8; ++t)
                        outf[(size_t)row * 128 + t * 16 + col0] =
                            (v[t] - mu) * rstd * s_r[t] + b_r[t];
                }
            }
        }
    }
}

extern "C" void kernel_launch(void* const* d_in, const int* in_sizes, int n_in,
                              void* d_out, int out_size, void* d_ws, size_t ws_size,
                              hipStream_t stream) {
    const float* h_cell = (const float*)d_in[0];
    const float* h_gene = (const float*)d_in[1];
    const int* src_cg = (const int*)d_in[2];
    const int* dst_cg = (const int*)d_in[3];
    const int* src_gc = (const int*)d_in[4];
    const int* dst_gc = (const int*)d_in[5];
    const int* src_cc = (const int*)d_in[6];
    const int* dst_cc = (const int*)d_in[7];
    const int* src_gg = (const int*)d_in[8];
    const int* dst_gg = (const int*)d_in[9];
    const float* W_cg = (const float*)d_in[10];
    const float* W_gc = (const float*)d_in[11];
    const float* W_cc = (const float*)d_in[12];
    const float* W_gg = (const float*)d_in[13];
    const float* b_cell = (const float*)d_in[14];
    const float* b_gene = (const float*)d_in[15];
    const float* ln_s_cell = (const float*)d_in[16];
    const float* ln_b_cell = (const float*)d_in[17];
    const float* ln_s_gene = (const float*)d_in[18];
    const float* ln_b_gene = (const float*)d_in[19];
    float* out = (float*)d_out;

    const int MPC = ((NCELL + GBM - 1) / GBM) * GBM;
    const int MPG = ((NGENE + GBM - 1) / GBM) * GBM;
    const int NB_C = (NCELL + 255) / 256;   // 391 bins (shift 8)
    const int NB_G = (NGENE + 15) / 16;     // 500 bins (shift 4)
    // fixed bin capacities: mean + >8 sigma (Poisson)
    const int CAP_GC = 4352;   // mean 3836
    const int CAP_CC = 3072;   // mean 2558
    const int CAP_CG = 3584;   // mean 3000
    const int CAP_GG = 768;    // mean 400

    char* wsb = (char*)d_ws;
    size_t off = 0;
    auto alloc = [&](size_t bytes) -> char* {
        char* p = wsb + off;
        off = (off + bytes + 255) & ~(size_t)255;
        return p;
    };
    unsigned short* Acat_c = (unsigned short*)alloc((size_t)MPC * 256 * 2);
    unsigned short* Acat_g = (unsigned short*)alloc((size_t)MPG * 256 * 2);
    // feature buffers carry one extra SENTINEL row (row N, zeroed in pre_k)
    unsigned short* hcb0 = (unsigned short*)alloc((size_t)(NCELL + 1) * DIM * 2);
    unsigned short* hgb0 = (unsigned short*)alloc((size_t)(NGENE + 1) * DIM * 2);
    unsigned short* hcb1 = (unsigned short*)alloc((size_t)(NCELL + 1) * DIM * 2);
    unsigned short* hgb1 = (unsigned short*)alloc((size_t)(NGENE + 1) * DIM * 2);
    unsigned short* Wp_cell = (unsigned short*)alloc(65536);
    unsigned short* Wp_gene = (unsigned short*)alloc(65536);
    int ndeg = 2 * NCELL + 2 * NGENE;
    int* degs = (int*)alloc((size_t)ndeg * 4);
    int* deg_gc = degs;
    int* deg_cc = degs + NCELL;
    int* deg_cg = degs + 2 * NCELL;
    int* deg_gg = degs + 2 * NCELL + NGENE;
    int* offs = (int*)alloc((size_t)ndeg * 4);
    int* off_gc = offs;
    int* off_cc = offs + NCELL;
    int* off_cg = offs + 2 * NCELL;
    int* off_gg = offs + 2 * NCELL + NGENE;
    int* bkt_gc = (int*)alloc((size_t)NB_C * CAP_GC * 4);
    int* bkt_cc = (int*)alloc((size_t)NB_C * CAP_CC * 4);
    int* bkt_cg = (int*)alloc((size_t)NB_G * CAP_CG * 4);
    int* bkt_gg = (int*)alloc((size_t)NB_G * CAP_GG * 4);
    unsigned* stg_gc = (unsigned*)alloc((size_t)NB_C * CAP_GC * 4);
    unsigned* stg_cc = (unsigned*)alloc((size_t)NB_C * CAP_CC * 4);
    unsigned* stg_cg = (unsigned*)alloc((size_t)NB_G * CAP_CG * 4);
    unsigned* stg_gg = (unsigned*)alloc((size_t)NB_G * CAP_GG * 4);
    int* binmem = (int*)alloc(4 * 512 * 4);

    // ---- binned CSR build params ----
    hipMemsetAsync(binmem, 0, 4 * 512 * 4, stream);
    const int nbk_gc = (NE_GC + 4095) / 4096;
    const int nbk_cc = (NE_CC + 4095) / 4096;
    const int nbk_cg = (NE_CG + 4095) / 4096;
    const int nbk_gg = (NE_GG + 4095) / 4096;
    auto mkrel = [&](const int* s, const int* d, int n, int shift, int nbins, int N, int cap,
                     int* deg, int* offg, int* bkt, int* bm, unsigned* stg,
                     int cblk0, int sblk0) {
        RelP r;
        r.src = s; r.dst = d; r.n = n; r.shift = shift; r.nbins = nbins; r.N = N; r.cap = cap;
        r.deg = deg; r.offg = offg; r.bkt = bkt;
        r.bcur = bm; r.stg = stg;
        r.cblk0 = cblk0; r.sblk0 = sblk0;
        return r;
    };
    RelP r0 = mkrel(src_gc, dst_gc, NE_GC, 8, NB_C, NCELL, CAP_GC, deg_gc, off_gc, bkt_gc,
                    binmem + 0 * 512, stg_gc, 0, 0);
    RelP r1 = mkrel(src_cc, dst_cc, NE_CC, 8, NB_C, NCELL, CAP_CC, deg_cc, off_cc, bkt_cc,
                    binmem + 1 * 512, stg_cc, nbk_gc, NB_C);
    RelP r2 = mkrel(src_cg, dst_cg, NE_CG, 4, NB_G, NGENE, CAP_CG, deg_cg, off_cg, bkt_cg,
                    binmem + 2 * 512, stg_cg, nbk_gc + nbk_cc, 2 * NB_C);
    RelP r3 = mkrel(src_gg, dst_gg, NE_GG, 4, NB_G, NGENE, CAP_GG, deg_gg, off_gg, bkt_gg,
                    binmem + 3 * 512, stg_gg, nbk_gc + nbk_cc + nbk_cg, 2 * NB_C + NB_G);
    const int fillBlocks = nbk_gc + nbk_cc + nbk_cg + nbk_gg;
    const int csrBlocks = 2 * NB_C + 2 * NB_G;

    // ---- merged pre-pass: fill | pack (32 blocks) | conv (+ sentinel zeroing) ----
    const int n2c = NCELL * DIM / 2, n2g = NGENE * DIM / 2;
    const int convCB = (n2c + 255) / 256;
    const int convGB = (n2g + 255) / 256;
    const int packBase = fillBlocks;
    const int convBase = fillBlocks + 32;
    const int preBlocks = convBase + convCB + convGB;
    pre_k<<<preBlocks, 256, 0, stream>>>(r0, r1, r2, r3, packBase, convBase, convCB,
                                         h_cell, hcb0, h_gene, hgb0, hcb1, hgb1, n2c, n2g,
                                         W_gc, W_cc, Wp_cell, W_cg, W_gg, Wp_gene);
    bin_csr4_k<<<csrBlocks, 256, 0, stream>>>(r0, r1, r2, r3);

    // ---- two shared layers ----
    const int gatherCB = NCELL / 4;           // 25000
    const int gatherGB = (NGENE + 3) / 4;     // 2000 (scheduled FIRST: longest jobs)
    const int gemmCB = MPC / GBM;             // 782
    const int gemmGB = MPG / GBM;             // 63
    const unsigned short* hc = hcb0;
    const unsigned short* hg = hgb0;
    for (int layer = 0; layer < 2; ++layer) {
        int final_ = (layer == 1);
        gather2_k<<<gatherGB + gatherCB, 256, 0, stream>>>(
            hc, hg,
            off_gc, deg_gc, bkt_gc, off_cc, deg_cc, bkt_cc,
            off_cg, deg_cg, bkt_cg, off_gg, deg_gg, bkt_gg,
            Acat_c, Acat_g, gatherGB);
        gemm2_ln_k<<<gemmCB + gemmGB, 256, 0, stream>>>(
            Acat_c, Acat_g, Wp_cell, Wp_gene, b_cell, b_gene,
            ln_s_cell, ln_b_cell, ln_s_gene, ln_b_gene,
            final_ ? nullptr : hcb1, final_ ? nullptr : hgb1,
            final_ ? out : nullptr, final_ ? out + (size_t)NCELL * DIM : nullptr,
            gemmCB);
        hc = hcb1;
        hg = hgb1;
    }
}

// Round 13
// 485.467 us; speedup vs baseline: 1.0624x; 1.0025x over previous
//
#include <hip/hip_runtime.h>

#define NCELL 100000
#define NGENE 8000
#define DIM   128
#define NE_CG 1500000
#define NE_GC 1500000
#define NE_CC 1000000
#define NE_GG 200000
#define SLOPE 0.05f
#define LN_EPS 1e-5f

typedef __attribute__((ext_vector_type(2))) _Float16 f16x2;
typedef __attribute__((ext_vector_type(8))) _Float16 f16x8;
typedef __attribute__((ext_vector_type(4))) float f32x4;

__device__ __forceinline__ unsigned short f2h(float x) {
    return __builtin_bit_cast(unsigned short, (_Float16)x);
}
__device__ __forceinline__ unsigned pack2h(float x, float y) {
    f16x2 h = { (_Float16)x, (_Float16)y };
    return __builtin_bit_cast(unsigned, h);
}
__device__ __forceinline__ f16x2 u2h2(unsigned u) {
    return __builtin_bit_cast(f16x2, u);
}

// ================= binned CSR build, fixed-capacity bins =================
struct RelP {
    const int* src; const int* dst; int n; int shift;
    int nbins; int N; int cap;
    int* deg; int* offg; int* bkt;
    int* bcur; unsigned* stg;
    int cblk0;   // first block id in fill region (pre_k)
    int sblk0;   // first block id in csr grid
};

// ---------------- merged pre-pass: fill (bins) | weight pack | f32->f16 conv ----------
// (r12 LDS-sorted fill writes were a null result; kept simple scattered form here.)
// Also zeroes the sentinel row (row N) of all four feature buffers.
__global__ __launch_bounds__(256)
void pre_k(RelP r0, RelP r1, RelP r2, RelP r3, int packBase, int convBase, int convCB,
           const float* __restrict__ h_cell, unsigned short* __restrict__ hcb,
           const float* __restrict__ h_gene, unsigned short* __restrict__ hgb,
           unsigned short* __restrict__ hcb1, unsigned short* __restrict__ hgb1,
           int n2c, int n2g,
           const float* __restrict__ WAc, const float* __restrict__ WBc,
           unsigned short* __restrict__ Wpc,
           const float* __restrict__ WAg, const float* __restrict__ WBg,
           unsigned short* __restrict__ Wpg) {
    __shared__ int cnt[512];
    __shared__ int basem[512];
    int b = blockIdx.x;
    int tid = threadIdx.x;

    if (b >= convBase) {
        // ---- f32 -> f16 conversion (cell then gene) ----
        int cb = b - convBase;
        const float* in; unsigned short* out; int i, n2;
        if (cb < convCB) { in = h_cell; out = hcb; n2 = n2c; i = cb * 256 + tid; }
        else             { in = h_gene; out = hgb; n2 = n2g; i = (cb - convCB) * 256 + tid; }
        if (i < n2) {
            float2 v = ((const float2*)in)[i];
            ((unsigned*)out)[i] = pack2h(v.x, v.y);
        }
        if (cb == 0) {
            // zero the sentinel rows (row NCELL / NGENE) of all four feature buffers
            if (tid < 64)       ((unsigned*)hcb )[n2c + tid]       = 0;
            else if (tid < 128) ((unsigned*)hcb1)[n2c + tid - 64]  = 0;
            else if (tid < 192) ((unsigned*)hgb )[n2g + tid - 128] = 0;
            else                ((unsigned*)hgb1)[n2g + tid - 192] = 0;
        }
        return;
    }
    if (b >= packBase) {
        // ---- weight pack: [W1;W2] -> MFMA B-frag layout (f16), 4 sub-blocks/block ----
        int sub = (b - packBase) * 4 + (tid >> 6);   // 0..127 (= original blockIdx)
        int lane = tid & 63;
        const float *WA, *WB; unsigned short* Wp; int bb;
        if (sub < 64) { WA = WAc; WB = WBc; Wp = Wpc; bb = sub; }
        else          { WA = WAg; WB = WBg; Wp = Wpg; bb = sub - 64; }
        int t = bb >> 3, cc = bb & 7;
        int n = t * 16 + (lane & 15);
        int k0 = cc * 32 + (lane >> 4) * 8;
        #pragma unroll
        for (int j = 0; j < 8; ++j) {
            int k = k0 + j;
            float x = (k < 128) ? WA[k * 128 + n] : WB[(k - 128) * 128 + n];
            Wp[((size_t)(bb * 64 + lane)) * 8 + j] = f2h(x);
        }
        return;
    }

    // ---- bin fill (fixed-cap bins) ----
    RelP R = (b >= r3.cblk0) ? r3 : (b >= r2.cblk0) ? r2 : (b >= r1.cblk0) ? r1 : r0;
    int lb = b - R.cblk0;
    cnt[tid] = 0; cnt[tid + 256] = 0;
    __syncthreads();
    int base = lb * 4096;
    int bins[16]; int ranks[16]; unsigned pk[16];
    #pragma unroll
    for (int it = 0; it < 16; ++it) {
        int i = base + it * 256 + tid;
        bins[it] = -1;
        if (i < R.n) {
            int d = R.dst[i];
            int bn = d >> R.shift;
            int dl = d & ((1 << R.shift) - 1);
            bins[it] = bn;
            pk[it] = (unsigned)R.src[i] | ((unsigned)dl << 20);
            ranks[it] = atomicAdd(&cnt[bn], 1);
        }
    }
    __syncthreads();
    if (cnt[tid])       basem[tid]       = atomicAdd(&R.bcur[tid],       cnt[tid]);
    if (cnt[tid + 256]) basem[tid + 256] = atomicAdd(&R.bcur[tid + 256], cnt[tid + 256]);
    __syncthreads();
    #pragma unroll
    for (int it = 0; it < 16; ++it)
        if (bins[it] >= 0) {
            int r = basem[bins[it]] + ranks[it];
            if (r >= R.cap) r = R.cap - 1;           // paranoia clamp (stays in own bin)
            R.stg[(size_t)bins[it] * R.cap + r] = pk[it];
        }
}

// counting-sort per bin; scatter goes to LDS, final global write is coalesced.
__global__ __launch_bounds__(256)
void bin_csr4_k(RelP r0, RelP r1, RelP r2, RelP r3) {
    int b = blockIdx.x;
    RelP R = (b >= r3.sblk0) ? r3 : (b >= r2.sblk0) ? r2 : (b >= r1.sblk0) ? r1 : r0;
    int lb = b - R.sblk0;
    int tid = threadIdx.x;
    int ebase = lb * R.cap;
    int cnt = R.bcur[lb]; if (cnt > R.cap) cnt = R.cap;
    __shared__ int degm[256];
    __shared__ int sc[256];
    __shared__ int cur[256];
    __shared__ int bktl[4352];   // >= max cap (CAP_GC)
    degm[tid] = 0;
    __syncthreads();
    for (int i = tid; i < cnt; i += 256)
        atomicAdd(&degm[(R.stg[ebase + i] >> 20) & 255], 1);
    __syncthreads();
    int x = degm[tid];
    sc[tid] = x;
    __syncthreads();
    for (int ofs = 1; ofs < 256; ofs <<= 1) {
        int t = (tid >= ofs) ? sc[tid - ofs] : 0;
        __syncthreads();
        sc[tid] += t;
        __syncthreads();
    }
    int excl = sc[tid] - x;
    cur[tid] = excl;
    int node = (lb << R.shift) + tid;
    if (tid < (1 << R.shift) && node < R.N) { R.deg[node] = x; R.offg[node] = ebase + excl; }
    __syncthreads();
    for (int i = tid; i < cnt; i += 256) {
        unsigned p = R.stg[ebase + i];
        int dl = (p >> 20) & 255;
        int r = atomicAdd(&cur[dl], 1);
        bktl[r] = (int)(p & 0xFFFFFu);
    }
    __syncthreads();
    for (int i = tid; i < cnt; i += 256)
        R.bkt[ebase + i] = bktl[i];
}

// ---------------- fused vectorized gather: sentinel-row unconditional f16 pk-add ------
// r10 configuration (verified 117 us): MERGED A/B loop (max MLP: 2 independent loads
// per t-iter — r11 showed splitting loses 12% to exposed latency), sentinel zero-row
// unconditional loads/adds (+0.0 exact in fp16), wave-uniform t-skip (s_cbranch, no
// register arrays -> no scratch), gene blocks FIRST (LJF). Full-exec __shfl only.
__global__ __launch_bounds__(256)
void gather2_k(const unsigned short* __restrict__ hc, const unsigned short* __restrict__ hg,
               const int* __restrict__ off_gc, const int* __restrict__ deg_gc, const int* __restrict__ bkt_gc,
               const int* __restrict__ off_cc, const int* __restrict__ deg_cc, const int* __restrict__ bkt_cc,
               const int* __restrict__ off_cg, const int* __restrict__ deg_cg, const int* __restrict__ bkt_cg,
               const int* __restrict__ off_gg, const int* __restrict__ deg_gg, const int* __restrict__ bkt_gg,
               unsigned short* __restrict__ Acat_c, unsigned short* __restrict__ Acat_g,
               int geneBlocks) {
    int wave = threadIdx.x >> 6, lane = threadIdx.x & 63;
    int g = lane >> 4, c = lane & 15;
    const unsigned short *hA, *hB;
    const int *offA, *degA, *bktA, *offB, *degB, *bktB;
    unsigned short* Aout; int node, N; int sentA, sentB;
    if ((int)blockIdx.x < geneBlocks) {
        node = blockIdx.x * 4 + wave; N = NGENE;
        hA = hc; offA = off_cg; degA = deg_cg; bktA = bkt_cg; sentA = NCELL;
        hB = hg; offB = off_gg; degB = deg_gg; bktB = bkt_gg; sentB = NGENE;
        Aout = Acat_g;
    } else {
        node = (blockIdx.x - geneBlocks) * 4 + wave; N = NCELL;
        hA = hg; offA = off_gc; degA = deg_gc; bktA = bkt_gc; sentA = NGENE;
        hB = hc; offB = off_cc; degB = deg_cc; bktB = bkt_cc; sentB = NCELL;
        Aout = Acat_c;
    }
    if (node >= N) return;

    int nA = degA[node], sA = offA[node];
    int nB = degB[node], sB = offB[node];

    f16x2 aA[4], aB[4];
    #pragma unroll
    for (int i = 0; i < 4; ++i) { aA[i] = (f16x2)(_Float16)0; aB[i] = (f16x2)(_Float16)0; }
    int mx = (nA > nB) ? nA : nB;

    for (int j0 = 0; j0 < mx; j0 += 32) {
        // preload 32 indices per relation (wave-uniform bounds); OOB slots get the
        // sentinel zero-row index so downstream loads/adds need no guards.
        int l32 = lane & 31;
        int jj = j0 + l32;
        int iv;
        if (lane < 32) { iv = sentA; if (jj < nA) iv = bktA[sA + jj]; }
        else           { iv = sentB; if (jj < nB) iv = bktB[sB + jj]; }
        int mxb = mx - j0;            // wave-uniform remaining edge count
        #pragma unroll
        for (int t = 0; t < 8; ++t) {
            if (t * 4 < mxb) {        // wave-uniform skip: s_cbranch, full exec inside
                int j = t * 4 + g;
                int sidxA = __shfl(iv, j);
                int sidxB = __shfl(iv, 32 + j);
                uint4 vA = *(const uint4*)(hA + (size_t)sidxA * DIM + c * 8);
                uint4 vB = *(const uint4*)(hB + (size_t)sidxB * DIM + c * 8);
                aA[0] += u2h2(vA.x); aA[1] += u2h2(vA.y);
                aA[2] += u2h2(vA.z); aA[3] += u2h2(vA.w);
                aB[0] += u2h2(vB.x); aB[1] += u2h2(vB.y);
                aB[2] += u2h2(vB.z); aB[3] += u2h2(vB.w);
            }
        }
    }

    // widen to f32, cross-group reduce, normalize, pack
    float fA[8], fB[8];
    #pragma unroll
    for (int i = 0; i < 4; ++i) {
        fA[2 * i]     = (float)aA[i][0]; fA[2 * i + 1] = (float)aA[i][1];
        fB[2 * i]     = (float)aB[i][0]; fB[2 * i + 1] = (float)aB[i][1];
    }
    #pragma unroll
    for (int i = 0; i < 8; ++i) {
        fA[i] += __shfl_xor(fA[i], 16); fA[i] += __shfl_xor(fA[i], 32);
        fB[i] += __shfl_xor(fB[i], 16); fB[i] += __shfl_xor(fB[i], 32);
    }
    float invA = 1.0f / fmaxf((float)nA, 1.0f);
    float invB = 1.0f / fmaxf((float)nB, 1.0f);
    uint4* outrow = (uint4*)(Aout + (size_t)node * 256);
    if (g == 0) {
        outrow[c] = make_uint4(pack2h(fA[0] * invA, fA[1] * invA), pack2h(fA[2] * invA, fA[3] * invA),
                               pack2h(fA[4] * invA, fA[5] * invA), pack2h(fA[6] * invA, fA[7] * invA));
    } else if (g == 1) {
        outrow[16 + c] = make_uint4(pack2h(fB[0] * invB, fB[1] * invB), pack2h(fB[2] * invB, fB[3] * invB),
                                    pack2h(fB[4] * invB, fB[5] * invB), pack2h(fB[6] * invB, fB[7] * invB));
    }
}

// ---------------- fused MFMA GEMM (f16) + bias + LeakyReLU + LN (cell & gene) ------------
// W read directly from global (64KB, L2-resident). r13: each wave now covers 64 output
// rows (4 mt-tiles) instead of 32 — one B-fragment feeds 4 MFMAs instead of 2, doubling
// arithmetic intensity per B-load (the theorized latency bottleneck). Per-output-row
// operation order unchanged -> bit-identical numerics. acc[4][8]=128 VGPR -> (256,2).
#define GBM 256
__global__ __launch_bounds__(256, 2)
void gemm2_ln_k(const unsigned short* __restrict__ Acat_c, const unsigned short* __restrict__ Acat_g,
                const unsigned short* __restrict__ Wp_c, const unsigned short* __restrict__ Wp_g,
                const float* __restrict__ bias_c, const float* __restrict__ bias_g,
                const float* __restrict__ ls_c, const float* __restrict__ lb_c,
                const float* __restrict__ ls_g, const float* __restrict__ lb_g,
                unsigned short* __restrict__ outh_c, unsigned short* __restrict__ outh_g,
                float* __restrict__ outf_c, float* __restrict__ outf_g,
                int cellBlocks) {
    const unsigned short *A, *Wp; const float *bias, *lns, *lnb;
    unsigned short* outh; float* outf; int M, mb;
    if ((int)blockIdx.x < cellBlocks) {
        A = Acat_c; Wp = Wp_c; bias = bias_c; lns = ls_c; lnb = lb_c;
        outh = outh_c; outf = outf_c; M = NCELL; mb = blockIdx.x;
    } else {
        A = Acat_g; Wp = Wp_g; bias = bias_g; lns = ls_g; lnb = lb_g;
        outh = outh_g; outf = outf_g; M = NGENE; mb = blockIdx.x - cellBlocks;
    }
    int tid = threadIdx.x;
    int wave = tid >> 6, lane = tid & 63;
    int col0 = lane & 15;
    int kq = lane >> 4;
    int m_base = mb * GBM + wave * 64;

    f32x4 acc[4][8];
    #pragma unroll
    for (int mt = 0; mt < 4; ++mt)
        #pragma unroll
        for (int t = 0; t < 8; ++t) acc[mt][t] = (f32x4){0.f, 0.f, 0.f, 0.f};

    const unsigned short* Ar0 = A + (size_t)(m_base + col0) * 256 + kq * 8;
    #pragma unroll
    for (int cc = 0; cc < 8; ++cc) {
        f16x8 a0 = *(const f16x8*)(Ar0 +  0 * 256 + cc * 32);
        f16x8 a1 = *(const f16x8*)(Ar0 + 16 * 256 + cc * 32);
        f16x8 a2 = *(const f16x8*)(Ar0 + 32 * 256 + cc * 32);
        f16x8 a3 = *(const f16x8*)(Ar0 + 48 * 256 + cc * 32);
        #pragma unroll
        for (int t = 0; t < 8; ++t) {
            f16x8 b = *(const f16x8*)(Wp + ((t * 8 + cc) * 64 + lane) * 8);
            acc[0][t] = __builtin_amdgcn_mfma_f32_16x16x32_f16(a0, b, acc[0][t], 0, 0, 0);
            acc[1][t] = __builtin_amdgcn_mfma_f32_16x16x32_f16(a1, b, acc[1][t], 0, 0, 0);
            acc[2][t] = __builtin_amdgcn_mfma_f32_16x16x32_f16(a2, b, acc[2][t], 0, 0, 0);
            acc[3][t] = __builtin_amdgcn_mfma_f32_16x16x32_f16(a3, b, acc[3][t], 0, 0, 0);
        }
    }

    float bias_r[8], s_r[8], b_r[8];
    #pragma unroll
    for (int t = 0; t < 8; ++t) {
        int col = t * 16 + col0;
        bias_r[t] = bias[col]; s_r[t] = lns[col]; b_r[t] = lnb[col];
    }
    #pragma unroll
    for (int mt = 0; mt < 4; ++mt) {
        #pragma unroll
        for (int r = 0; r < 4; ++r) {
            int row = m_base + mt * 16 + kq * 4 + r;
            float v[8]; float sum = 0.f, sq = 0.f;
            #pragma unroll
            for (int t = 0; t < 8; ++t) {
                float x = acc[mt][t][r] + bias_r[t];
                x = (x >= 0.f) ? x : SLOPE * x;
                v[t] = x; sum += x; sq += x * x;
            }
            #pragma unroll
            for (int ofs = 1; ofs <= 8; ofs <<= 1) {
                sum += __shfl_xor(sum, ofs);
                sq  += __shfl_xor(sq, ofs);
            }
            float mu = sum * (1.0f / 128.0f);
            float var = sq * (1.0f / 128.0f) - mu * mu;
            float rstd = rsqrtf(var + LN_EPS);
            if (row < M) {
                if (outh) {
                    #pragma unroll
                    for (int t = 0; t < 8; ++t)
                        outh[(size_t)row * 128 + t * 16 + col0] =
                            f2h((v[t] - mu) * rstd * s_r[t] + b_r[t]);
                } else {
                    #pragma unroll
                    for (int t = 0; t < 8; ++t)
                        outf[(size_t)row * 128 + t * 16 + col0] =
                            (v[t] - mu) * rstd * s_r[t] + b_r[t];
                }
            }
        }
    }
}

extern "C" void kernel_launch(void* const* d_in, const int* in_sizes, int n_in,
                              void* d_out, int out_size, void* d_ws, size_t ws_size,
                              hipStream_t stream) {
    const float* h_cell = (const float*)d_in[0];
    const float* h_gene = (const float*)d_in[1];
    const int* src_cg = (const int*)d_in[2];
    const int* dst_cg = (const int*)d_in[3];
    const int* src_gc = (const int*)d_in[4];
    const int* dst_gc = (const int*)d_in[5];
    const int* src_cc = (const int*)d_in[6];
    const int* dst_cc = (const int*)d_in[7];
    const int* src_gg = (const int*)d_in[8];
    const int* dst_gg = (const int*)d_in[9];
    const float* W_cg = (const float*)d_in[10];
    const float* W_gc = (const float*)d_in[11];
    const float* W_cc = (const float*)d_in[12];
    const float* W_gg = (const float*)d_in[13];
    const float* b_cell = (const float*)d_in[14];
    const float* b_gene = (const float*)d_in[15];
    const float* ln_s_cell = (const float*)d_in[16];
    const float* ln_b_cell = (const float*)d_in[17];
    const float* ln_s_gene = (const float*)d_in[18];
    const float* ln_b_gene = (const float*)d_in[19];
    float* out = (float*)d_out;

    const int MPC = ((NCELL + GBM - 1) / GBM) * GBM;   // 100352
    const int MPG = ((NGENE + GBM - 1) / GBM) * GBM;   // 8192
    const int NB_C = (NCELL + 255) / 256;   // 391 bins (shift 8)
    const int NB_G = (NGENE + 15) / 16;     // 500 bins (shift 4)
    // fixed bin capacities: mean + >8 sigma (Poisson)
    const int CAP_GC = 4352;   // mean 3836
    const int CAP_CC = 3072;   // mean 2558
    const int CAP_CG = 3584;   // mean 3000
    const int CAP_GG = 768;    // mean 400

    char* wsb = (char*)d_ws;
    size_t off = 0;
    auto alloc = [&](size_t bytes) -> char* {
        char* p = wsb + off;
        off = (off + bytes + 255) & ~(size_t)255;
        return p;
    };
    unsigned short* Acat_c = (unsigned short*)alloc((size_t)MPC * 256 * 2);
    unsigned short* Acat_g = (unsigned short*)alloc((size_t)MPG * 256 * 2);
    // feature buffers carry one extra SENTINEL row (row N, zeroed in pre_k)
    unsigned short* hcb0 = (unsigned short*)alloc((size_t)(NCELL + 1) * DIM * 2);
    unsigned short* hgb0 = (unsigned short*)alloc((size_t)(NGENE + 1) * DIM * 2);
    unsigned short* hcb1 = (unsigned short*)alloc((size_t)(NCELL + 1) * DIM * 2);
    unsigned short* hgb1 = (unsigned short*)alloc((size_t)(NGENE + 1) * DIM * 2);
    unsigned short* Wp_cell = (unsigned short*)alloc(65536);
    unsigned short* Wp_gene = (unsigned short*)alloc(65536);
    int ndeg = 2 * NCELL + 2 * NGENE;
    int* degs = (int*)alloc((size_t)ndeg * 4);
    int* deg_gc = degs;
    int* deg_cc = degs + NCELL;
    int* deg_cg = degs + 2 * NCELL;
    int* deg_gg = degs + 2 * NCELL + NGENE;
    int* offs = (int*)alloc((size_t)ndeg * 4);
    int* off_gc = offs;
    int* off_cc = offs + NCELL;
    int* off_cg = offs + 2 * NCELL;
    int* off_gg = offs + 2 * NCELL + NGENE;
    int* bkt_gc = (int*)alloc((size_t)NB_C * CAP_GC * 4);
    int* bkt_cc = (int*)alloc((size_t)NB_C * CAP_CC * 4);
    int* bkt_cg = (int*)alloc((size_t)NB_G * CAP_CG * 4);
    int* bkt_gg = (int*)alloc((size_t)NB_G * CAP_GG * 4);
    unsigned* stg_gc = (unsigned*)alloc((size_t)NB_C * CAP_GC * 4);
    unsigned* stg_cc = (unsigned*)alloc((size_t)NB_C * CAP_CC * 4);
    unsigned* stg_cg = (unsigned*)alloc((size_t)NB_G * CAP_CG * 4);
    unsigned* stg_gg = (unsigned*)alloc((size_t)NB_G * CAP_GG * 4);
    int* binmem = (int*)alloc(4 * 512 * 4);

    // ---- binned CSR build params ----
    hipMemsetAsync(binmem, 0, 4 * 512 * 4, stream);
    const int nbk_gc = (NE_GC + 4095) / 4096;
    const int nbk_cc = (NE_CC + 4095) / 4096;
    const int nbk_cg = (NE_CG + 4095) / 4096;
    const int nbk_gg = (NE_GG + 4095) / 4096;
    auto mkrel = [&](const int* s, const int* d, int n, int shift, int nbins, int N, int cap,
                     int* deg, int* offg, int* bkt, int* bm, unsigned* stg,
                     int cblk0, int sblk0) {
        RelP r;
        r.src = s; r.dst = d; r.n = n; r.shift = shift; r.nbins = nbins; r.N = N; r.cap = cap;
        r.deg = deg; r.offg = offg; r.bkt = bkt;
        r.bcur = bm; r.stg = stg;
        r.cblk0 = cblk0; r.sblk0 = sblk0;
        return r;
    };
    RelP r0 = mkrel(src_gc, dst_gc, NE_GC, 8, NB_C, NCELL, CAP_GC, deg_gc, off_gc, bkt_gc,
                    binmem + 0 * 512, stg_gc, 0, 0);
    RelP r1 = mkrel(src_cc, dst_cc, NE_CC, 8, NB_C, NCELL, CAP_CC, deg_cc, off_cc, bkt_cc,
                    binmem + 1 * 512, stg_cc, nbk_gc, NB_C);
    RelP r2 = mkrel(src_cg, dst_cg, NE_CG, 4, NB_G, NGENE, CAP_CG, deg_cg, off_cg, bkt_cg,
                    binmem + 2 * 512, stg_cg, nbk_gc + nbk_cc, 2 * NB_C);
    RelP r3 = mkrel(src_gg, dst_gg, NE_GG, 4, NB_G, NGENE, CAP_GG, deg_gg, off_gg, bkt_gg,
                    binmem + 3 * 512, stg_gg, nbk_gc + nbk_cc + nbk_cg, 2 * NB_C + NB_G);
    const int fillBlocks = nbk_gc + nbk_cc + nbk_cg + nbk_gg;
    const int csrBlocks = 2 * NB_C + 2 * NB_G;

    // ---- merged pre-pass: fill | pack (32 blocks) | conv (+ sentinel zeroing) ----
    const int n2c = NCELL * DIM / 2, n2g = NGENE * DIM / 2;
    const int convCB = (n2c + 255) / 256;
    const int convGB = (n2g + 255) / 256;
    const int packBase = fillBlocks;
    const int convBase = fillBlocks + 32;
    const int preBlocks = convBase + convCB + convGB;
    pre_k<<<preBlocks, 256, 0, stream>>>(r0, r1, r2, r3, packBase, convBase, convCB,
                                         h_cell, hcb0, h_gene, hgb0, hcb1, hgb1, n2c, n2g,
                                         W_gc, W_cc, Wp_cell, W_cg, W_gg, Wp_gene);
    bin_csr4_k<<<csrBlocks, 256, 0, stream>>>(r0, r1, r2, r3);

    // ---- two shared layers ----
    const int gatherCB = NCELL / 4;           // 25000
    const int gatherGB = (NGENE + 3) / 4;     // 2000 (scheduled FIRST: longest jobs)
    const int gemmCB = MPC / GBM;             // 392
    const int gemmGB = MPG / GBM;             // 32
    const unsigned short* hc = hcb0;
    const unsigned short* hg = hgb0;
    for (int layer = 0; layer < 2; ++layer) {
        int final_ = (layer == 1);
        gather2_k<<<gatherGB + gatherCB, 256, 0, stream>>>(
            hc, hg,
            off_gc, deg_gc, bkt_gc, off_cc, deg_cc, bkt_cc,
            off_cg, deg_cg, bkt_cg, off_gg, deg_gg, bkt_gg,
            Acat_c, Acat_g, gatherGB);
        gemm2_ln_k<<<gemmCB + gemmGB, 256, 0, stream>>>(
            Acat_c, Acat_g, Wp_cell, Wp_gene, b_cell, b_gene,
            ln_s_cell, ln_b_cell, ln_s_gene, ln_b_gene,
            final_ ? nullptr : hcb1, final_ ? nullptr : hgb1,
            final_ ? out : nullptr, final_ ? out + (size_t)NCELL * DIM : nullptr,
            gemmCB);
        hc = hcb1;
        hg = hgb1;
    }
}

// Round 14
// 467.186 us; speedup vs baseline: 1.1040x; 1.0391x over previous
//
#include <hip/hip_runtime.h>

#define NCELL 100000
#define NGENE 8000
#define DIM   128
#define NE_CG 1500000
#define NE_GC 1500000
#define NE_CC 1000000
#define NE_GG 200000
#define SLOPE 0.05f
#define LN_EPS 1e-5f

typedef __attribute__((ext_vector_type(2))) _Float16 f16x2;
typedef __attribute__((ext_vector_type(8))) _Float16 f16x8;
typedef __attribute__((ext_vector_type(4))) float f32x4;

__device__ __forceinline__ unsigned short f2h(float x) {
    return __builtin_bit_cast(unsigned short, (_Float16)x);
}
__device__ __forceinline__ unsigned pack2h(float x, float y) {
    f16x2 h = { (_Float16)x, (_Float16)y };
    return __builtin_bit_cast(unsigned, h);
}
__device__ __forceinline__ f16x2 u2h2(unsigned u) {
    return __builtin_bit_cast(f16x2, u);
}

// ================= binned CSR build, fixed-capacity bins =================
struct RelP {
    const int* src; const int* dst; int n; int shift;
    int nbins; int N; int cap;
    int* deg; int* offg; int* bkt;
    int* bcur; unsigned* stg;
    int cblk0;   // first block id in fill region (pre_k)
    int sblk0;   // first block id in csr grid
};

// ---------------- merged pre-pass: fill (bins) | weight pack | f32->f16 conv ----------
// Conv uses float4 loads (bit-identical values, half the instructions).
// Also zeroes the sentinel row (row N) of all four feature buffers.
__global__ __launch_bounds__(256)
void pre_k(RelP r0, RelP r1, RelP r2, RelP r3, int packBase, int convBase, int convCB,
           const float* __restrict__ h_cell, unsigned short* __restrict__ hcb,
           const float* __restrict__ h_gene, unsigned short* __restrict__ hgb,
           unsigned short* __restrict__ hcb1, unsigned short* __restrict__ hgb1,
           int n4c, int n4g,
           const float* __restrict__ WAc, const float* __restrict__ WBc,
           unsigned short* __restrict__ Wpc,
           const float* __restrict__ WAg, const float* __restrict__ WBg,
           unsigned short* __restrict__ Wpg) {
    __shared__ int cnt[512];
    __shared__ int basem[512];
    int b = blockIdx.x;
    int tid = threadIdx.x;

    if (b >= convBase) {
        // ---- f32 -> f16 conversion (cell then gene), float4-wide ----
        int cb = b - convBase;
        const float* in; unsigned short* out; int i, n4;
        if (cb < convCB) { in = h_cell; out = hcb; n4 = n4c; i = cb * 256 + tid; }
        else             { in = h_gene; out = hgb; n4 = n4g; i = (cb - convCB) * 256 + tid; }
        if (i < n4) {
            float4 v = ((const float4*)in)[i];
            ((uint2*)out)[i] = make_uint2(pack2h(v.x, v.y), pack2h(v.z, v.w));
        }
        if (cb == 0) {
            // zero the sentinel rows (row NCELL / NGENE) of all four feature buffers
            int n2c = n4c * 2, n2g = n4g * 2;
            if (tid < 64)       ((unsigned*)hcb )[n2c + tid]       = 0;
            else if (tid < 128) ((unsigned*)hcb1)[n2c + tid - 64]  = 0;
            else if (tid < 192) ((unsigned*)hgb )[n2g + tid - 128] = 0;
            else                ((unsigned*)hgb1)[n2g + tid - 192] = 0;
        }
        return;
    }
    if (b >= packBase) {
        // ---- weight pack: [W1;W2] -> MFMA B-frag layout (f16), 4 sub-blocks/block ----
        int sub = (b - packBase) * 4 + (tid >> 6);   // 0..127 (= original blockIdx)
        int lane = tid & 63;
        const float *WA, *WB; unsigned short* Wp; int bb;
        if (sub < 64) { WA = WAc; WB = WBc; Wp = Wpc; bb = sub; }
        else          { WA = WAg; WB = WBg; Wp = Wpg; bb = sub - 64; }
        int t = bb >> 3, cc = bb & 7;
        int n = t * 16 + (lane & 15);
        int k0 = cc * 32 + (lane >> 4) * 8;
        #pragma unroll
        for (int j = 0; j < 8; ++j) {
            int k = k0 + j;
            float x = (k < 128) ? WA[k * 128 + n] : WB[(k - 128) * 128 + n];
            Wp[((size_t)(bb * 64 + lane)) * 8 + j] = f2h(x);
        }
        return;
    }

    // ---- bin fill (fixed-cap bins) ----
    RelP R = (b >= r3.cblk0) ? r3 : (b >= r2.cblk0) ? r2 : (b >= r1.cblk0) ? r1 : r0;
    int lb = b - R.cblk0;
    cnt[tid] = 0; cnt[tid + 256] = 0;
    __syncthreads();
    int base = lb * 4096;
    int bins[16]; int ranks[16]; unsigned pk[16];
    #pragma unroll
    for (int it = 0; it < 16; ++it) {
        int i = base + it * 256 + tid;
        bins[it] = -1;
        if (i < R.n) {
            int d = R.dst[i];
            int bn = d >> R.shift;
            int dl = d & ((1 << R.shift) - 1);
            bins[it] = bn;
            pk[it] = (unsigned)R.src[i] | ((unsigned)dl << 20);
            ranks[it] = atomicAdd(&cnt[bn], 1);
        }
    }
    __syncthreads();
    if (cnt[tid])       basem[tid]       = atomicAdd(&R.bcur[tid],       cnt[tid]);
    if (cnt[tid + 256]) basem[tid + 256] = atomicAdd(&R.bcur[tid + 256], cnt[tid + 256]);
    __syncthreads();
    #pragma unroll
    for (int it = 0; it < 16; ++it)
        if (bins[it] >= 0) {
            int r = basem[bins[it]] + ranks[it];
            if (r >= R.cap) r = R.cap - 1;           // paranoia clamp (stays in own bin)
            R.stg[(size_t)bins[it] * R.cap + r] = pk[it];
        }
}

// counting-sort per bin; scatter goes to LDS, final global write is coalesced.
__global__ __launch_bounds__(256)
void bin_csr4_k(RelP r0, RelP r1, RelP r2, RelP r3) {
    int b = blockIdx.x;
    RelP R = (b >= r3.sblk0) ? r3 : (b >= r2.sblk0) ? r2 : (b >= r1.sblk0) ? r1 : r0;
    int lb = b - R.sblk0;
    int tid = threadIdx.x;
    int ebase = lb * R.cap;
    int cnt = R.bcur[lb]; if (cnt > R.cap) cnt = R.cap;
    __shared__ int degm[256];
    __shared__ int sc[256];
    __shared__ int cur[256];
    __shared__ int bktl[4352];   // >= max cap (CAP_GC)
    degm[tid] = 0;
    __syncthreads();
    for (int i = tid; i < cnt; i += 256)
        atomicAdd(&degm[(R.stg[ebase + i] >> 20) & 255], 1);
    __syncthreads();
    int x = degm[tid];
    sc[tid] = x;
    __syncthreads();
    for (int ofs = 1; ofs < 256; ofs <<= 1) {
        int t = (tid >= ofs) ? sc[tid - ofs] : 0;
        __syncthreads();
        sc[tid] += t;
        __syncthreads();
    }
    int excl = sc[tid] - x;
    cur[tid] = excl;
    int node = (lb << R.shift) + tid;
    if (tid < (1 << R.shift) && node < R.N) { R.deg[node] = x; R.offg[node] = ebase + excl; }
    __syncthreads();
    for (int i = tid; i < cnt; i += 256) {
        unsigned p = R.stg[ebase + i];
        int dl = (p >> 20) & 255;
        int r = atomicAdd(&cur[dl], 1);
        bktl[r] = (int)(p & 0xFFFFFu);
    }
    __syncthreads();
    for (int i = tid; i < cnt; i += 256)
        R.bkt[ebase + i] = bktl[i];
}

// ---------------- fused vectorized gather: sentinel-row unconditional f16 pk-add ------
// r10 configuration (verified 117 us): MERGED A/B loop (max MLP), sentinel zero-row
// unconditional loads/adds, wave-uniform t-skip, gene blocks FIRST. Untouched.
__global__ __launch_bounds__(256)
void gather2_k(const unsigned short* __restrict__ hc, const unsigned short* __restrict__ hg,
               const int* __restrict__ off_gc, const int* __restrict__ deg_gc, const int* __restrict__ bkt_gc,
               const int* __restrict__ off_cc, const int* __restrict__ deg_cc, const int* __restrict__ bkt_cc,
               const int* __restrict__ off_cg, const int* __restrict__ deg_cg, const int* __restrict__ bkt_cg,
               const int* __restrict__ off_gg, const int* __restrict__ deg_gg, const int* __restrict__ bkt_gg,
               unsigned short* __restrict__ Acat_c, unsigned short* __restrict__ Acat_g,
               int geneBlocks) {
    int wave = threadIdx.x >> 6, lane = threadIdx.x & 63;
    int g = lane >> 4, c = lane & 15;
    const unsigned short *hA, *hB;
    const int *offA, *degA, *bktA, *offB, *degB, *bktB;
    unsigned short* Aout; int node, N; int sentA, sentB;
    if ((int)blockIdx.x < geneBlocks) {
        node = blockIdx.x * 4 + wave; N = NGENE;
        hA = hc; offA = off_cg; degA = deg_cg; bktA = bkt_cg; sentA = NCELL;
        hB = hg; offB = off_gg; degB = deg_gg; bktB = bkt_gg; sentB = NGENE;
        Aout = Acat_g;
    } else {
        node = (blockIdx.x - geneBlocks) * 4 + wave; N = NCELL;
        hA = hg; offA = off_gc; degA = deg_gc; bktA = bkt_gc; sentA = NGENE;
        hB = hc; offB = off_cc; degB = deg_cc; bktB = bkt_cc; sentB = NCELL;
        Aout = Acat_c;
    }
    if (node >= N) return;

    int nA = degA[node], sA = offA[node];
    int nB = degB[node], sB = offB[node];

    f16x2 aA[4], aB[4];
    #pragma unroll
    for (int i = 0; i < 4; ++i) { aA[i] = (f16x2)(_Float16)0; aB[i] = (f16x2)(_Float16)0; }
    int mx = (nA > nB) ? nA : nB;

    for (int j0 = 0; j0 < mx; j0 += 32) {
        int l32 = lane & 31;
        int jj = j0 + l32;
        int iv;
        if (lane < 32) { iv = sentA; if (jj < nA) iv = bktA[sA + jj]; }
        else           { iv = sentB; if (jj < nB) iv = bktB[sB + jj]; }
        int mxb = mx - j0;            // wave-uniform remaining edge count
        #pragma unroll
        for (int t = 0; t < 8; ++t) {
            if (t * 4 < mxb) {        // wave-uniform skip: s_cbranch, full exec inside
                int j = t * 4 + g;
                int sidxA = __shfl(iv, j);
                int sidxB = __shfl(iv, 32 + j);
                uint4 vA = *(const uint4*)(hA + (size_t)sidxA * DIM + c * 8);
                uint4 vB = *(const uint4*)(hB + (size_t)sidxB * DIM + c * 8);
                aA[0] += u2h2(vA.x); aA[1] += u2h2(vA.y);
                aA[2] += u2h2(vA.z); aA[3] += u2h2(vA.w);
                aB[0] += u2h2(vB.x); aB[1] += u2h2(vB.y);
                aB[2] += u2h2(vB.z); aB[3] += u2h2(vB.w);
            }
        }
    }

    // widen to f32, cross-group reduce, normalize, pack
    float fA[8], fB[8];
    #pragma unroll
    for (int i = 0; i < 4; ++i) {
        fA[2 * i]     = (float)aA[i][0]; fA[2 * i + 1] = (float)aA[i][1];
        fB[2 * i]     = (float)aB[i][0]; fB[2 * i + 1] = (float)aB[i][1];
    }
    #pragma unroll
    for (int i = 0; i < 8; ++i) {
        fA[i] += __shfl_xor(fA[i], 16); fA[i] += __shfl_xor(fA[i], 32);
        fB[i] += __shfl_xor(fB[i], 16); fB[i] += __shfl_xor(fB[i], 32);
    }
    float invA = 1.0f / fmaxf((float)nA, 1.0f);
    float invB = 1.0f / fmaxf((float)nB, 1.0f);
    uint4* outrow = (uint4*)(Aout + (size_t)node * 256);
    if (g == 0) {
        outrow[c] = make_uint4(pack2h(fA[0] * invA, fA[1] * invA), pack2h(fA[2] * invA, fA[3] * invA),
                               pack2h(fA[4] * invA, fA[5] * invA), pack2h(fA[6] * invA, fA[7] * invA));
    } else if (g == 1) {
        outrow[16 + c] = make_uint4(pack2h(fB[0] * invB, fB[1] * invB), pack2h(fB[2] * invB, fB[3] * invB),
                                    pack2h(fB[4] * invB, fB[5] * invB), pack2h(fB[6] * invB, fB[7] * invB));
    }
}

// ---------------- fused MFMA GEMM (f16) + bias + LeakyReLU + LN (cell & gene) ------------
// r14: B staged in LDS in TWO 32KB halves (cc 0-3, then 4-7) -> ds_read B (no TA/L2
// latency) at 3 blocks/CU (12 waves/CU) instead of r4's 64KB/2 blocks or r5's
// global-B. cc order (0..7, t inner) unchanged -> bit-identical accumulation.
#define GBM 128
__global__ __launch_bounds__(256, 3)
void gemm2_ln_k(const unsigned short* __restrict__ Acat_c, const unsigned short* __restrict__ Acat_g,
                const unsigned short* __restrict__ Wp_c, const unsigned short* __restrict__ Wp_g,
                const float* __restrict__ bias_c, const float* __restrict__ bias_g,
                const float* __restrict__ ls_c, const float* __restrict__ lb_c,
                const float* __restrict__ ls_g, const float* __restrict__ lb_g,
                unsigned short* __restrict__ outh_c, unsigned short* __restrict__ outh_g,
                float* __restrict__ outf_c, float* __restrict__ outf_g,
                int cellBlocks) {
    const unsigned short *A, *Wp; const float *bias, *lns, *lnb;
    unsigned short* outh; float* outf; int M, mb;
    if ((int)blockIdx.x < cellBlocks) {
        A = Acat_c; Wp = Wp_c; bias = bias_c; lns = ls_c; lnb = lb_c;
        outh = outh_c; outf = outf_c; M = NCELL; mb = blockIdx.x;
    } else {
        A = Acat_g; Wp = Wp_g; bias = bias_g; lns = ls_g; lnb = lb_g;
        outh = outh_g; outf = outf_g; M = NGENE; mb = blockIdx.x - cellBlocks;
    }
    __shared__ unsigned short Ws[16384];   // 32 KB: one half (32 B-fragments of 1KB)
    int tid = threadIdx.x;
    int wave = tid >> 6, lane = tid & 63;
    int col0 = lane & 15;
    int kq = lane >> 4;
    int m_base = mb * GBM + wave * 32;

    f32x4 acc[2][8];
    #pragma unroll
    for (int mt = 0; mt < 2; ++mt)
        #pragma unroll
        for (int t = 0; t < 8; ++t) acc[mt][t] = (f32x4){0.f, 0.f, 0.f, 0.f};

    const unsigned short* Ar0 = A + (size_t)(m_base + col0) * 256 + kq * 8;
    const unsigned short* Ar1 = Ar0 + 16 * 256;

    #pragma unroll
    for (int cch = 0; cch < 2; ++cch) {
        // stage fragments f = t*8 + cch*4 + cc2 (t=0..7, cc2=0..3) -> LDS slot t*4+cc2
        __syncthreads();
        {
            const uint4* s = (const uint4*)Wp;
            uint4* d = (uint4*)Ws;
            #pragma unroll
            for (int k = 0; k < 8; ++k) {
                int i = k * 256 + tid;          // 0..2047 (2048 uint4 = 32KB)
                int fl = i >> 6;                // 0..31: t*4+cc2
                int within = i & 63;
                int f = (fl >> 2) * 8 + cch * 4 + (fl & 3);
                d[i] = s[f * 64 + within];
            }
        }
        __syncthreads();
        #pragma unroll
        for (int cc2 = 0; cc2 < 4; ++cc2) {
            int cc = cch * 4 + cc2;
            f16x8 a0 = *(const f16x8*)(Ar0 + cc * 32);
            f16x8 a1 = *(const f16x8*)(Ar1 + cc * 32);
            #pragma unroll
            for (int t = 0; t < 8; ++t) {
                f16x8 b = *(const f16x8*)(Ws + ((t * 4 + cc2) * 64 + lane) * 8);
                acc[0][t] = __builtin_amdgcn_mfma_f32_16x16x32_f16(a0, b, acc[0][t], 0, 0, 0);
                acc[1][t] = __builtin_amdgcn_mfma_f32_16x16x32_f16(a1, b, acc[1][t], 0, 0, 0);
            }
        }
    }

    float bias_r[8], s_r[8], b_r[8];
    #pragma unroll
    for (int t = 0; t < 8; ++t) {
        int col = t * 16 + col0;
        bias_r[t] = bias[col]; s_r[t] = lns[col]; b_r[t] = lnb[col];
    }
    #pragma unroll
    for (int mt = 0; mt < 2; ++mt) {
        #pragma unroll
        for (int r = 0; r < 4; ++r) {
            int row = m_base + mt * 16 + kq * 4 + r;
            float v[8]; float sum = 0.f, sq = 0.f;
            #pragma unroll
            for (int t = 0; t < 8; ++t) {
                float x = acc[mt][t][r] + bias_r[t];
                x = (x >= 0.f) ? x : SLOPE * x;
                v[t] = x; sum += x; sq += x * x;
            }
            #pragma unroll
            for (int ofs = 1; ofs <= 8; ofs <<= 1) {
                sum += __shfl_xor(sum, ofs);
                sq  += __shfl_xor(sq, ofs);
            }
            float mu = sum * (1.0f / 128.0f);
            float var = sq * (1.0f / 128.0f) - mu * mu;
            float rstd = rsqrtf(var + LN_EPS);
            if (row < M) {
                if (outh) {
                    #pragma unroll
                    for (int t = 0; t < 8; ++t)
                        outh[(size_t)row * 128 + t * 16 + col0] =
                            f2h((v[t] - mu) * rstd * s_r[t] + b_r[t]);
                } else {
                    #pragma unroll
                    for (int t = 0; t < 8; ++t)
                        outf[(size_t)row * 128 + t * 16 + col0] =
                            (v[t] - mu) * rstd * s_r[t] + b_r[t];
                }
            }
        }
    }
}

extern "C" void kernel_launch(void* const* d_in, const int* in_sizes, int n_in,
                              void* d_out, int out_size, void* d_ws, size_t ws_size,
                              hipStream_t stream) {
    const float* h_cell = (const float*)d_in[0];
    const float* h_gene = (const float*)d_in[1];
    const int* src_cg = (const int*)d_in[2];
    const int* dst_cg = (const int*)d_in[3];
    const int* src_gc = (const int*)d_in[4];
    const int* dst_gc = (const int*)d_in[5];
    const int* src_cc = (const int*)d_in[6];
    const int* dst_cc = (const int*)d_in[7];
    const int* src_gg = (const int*)d_in[8];
    const int* dst_gg = (const int*)d_in[9];
    const float* W_cg = (const float*)d_in[10];
    const float* W_gc = (const float*)d_in[11];
    const float* W_cc = (const float*)d_in[12];
    const float* W_gg = (const float*)d_in[13];
    const float* b_cell = (const float*)d_in[14];
    const float* b_gene = (const float*)d_in[15];
    const float* ln_s_cell = (const float*)d_in[16];
    const float* ln_b_cell = (const float*)d_in[17];
    const float* ln_s_gene = (const float*)d_in[18];
    const float* ln_b_gene = (const float*)d_in[19];
    float* out = (float*)d_out;

    const int MPC = ((NCELL + GBM - 1) / GBM) * GBM;
    const int MPG = ((NGENE + GBM - 1) / GBM) * GBM;
    const int NB_C = (NCELL + 255) / 256;   // 391 bins (shift 8)
    const int NB_G = (NGENE + 15) / 16;     // 500 bins (shift 4)
    // fixed bin capacities: mean + >8 sigma (Poisson)
    const int CAP_GC = 4352;   // mean 3836
    const int CAP_CC = 3072;   // mean 2558
    const int CAP_CG = 3584;   // mean 3000
    const int CAP_GG = 768;    // mean 400

    char* wsb = (char*)d_ws;
    size_t off = 0;
    auto alloc = [&](size_t bytes) -> char* {
        char* p = wsb + off;
        off = (off + bytes + 255) & ~(size_t)255;
        return p;
    };
    unsigned short* Acat_c = (unsigned short*)alloc((size_t)MPC * 256 * 2);
    unsigned short* Acat_g = (unsigned short*)alloc((size_t)MPG * 256 * 2);
    // feature buffers carry one extra SENTINEL row (row N, zeroed in pre_k)
    unsigned short* hcb0 = (unsigned short*)alloc((size_t)(NCELL + 1) * DIM * 2);
    unsigned short* hgb0 = (unsigned short*)alloc((size_t)(NGENE + 1) * DIM * 2);
    unsigned short* hcb1 = (unsigned short*)alloc((size_t)(NCELL + 1) * DIM * 2);
    unsigned short* hgb1 = (unsigned short*)alloc((size_t)(NGENE + 1) * DIM * 2);
    unsigned short* Wp_cell = (unsigned short*)alloc(65536);
    unsigned short* Wp_gene = (unsigned short*)alloc(65536);
    int ndeg = 2 * NCELL + 2 * NGENE;
    int* degs = (int*)alloc((size_t)ndeg * 4);
    int* deg_gc = degs;
    int* deg_cc = degs + NCELL;
    int* deg_cg = degs + 2 * NCELL;
    int* deg_gg = degs + 2 * NCELL + NGENE;
    int* offs = (int*)alloc((size_t)ndeg * 4);
    int* off_gc = offs;
    int* off_cc = offs + NCELL;
    int* off_cg = offs + 2 * NCELL;
    int* off_gg = offs + 2 * NCELL + NGENE;
    int* bkt_gc = (int*)alloc((size_t)NB_C * CAP_GC * 4);
    int* bkt_cc = (int*)alloc((size_t)NB_C * CAP_CC * 4);
    int* bkt_cg = (int*)alloc((size_t)NB_G * CAP_CG * 4);
    int* bkt_gg = (int*)alloc((size_t)NB_G * CAP_GG * 4);
    unsigned* stg_gc = (unsigned*)alloc((size_t)NB_C * CAP_GC * 4);
    unsigned* stg_cc = (unsigned*)alloc((size_t)NB_C * CAP_CC * 4);
    unsigned* stg_cg = (unsigned*)alloc((size_t)NB_G * CAP_CG * 4);
    unsigned* stg_gg = (unsigned*)alloc((size_t)NB_G * CAP_GG * 4);
    int* binmem = (int*)alloc(4 * 512 * 4);

    // ---- binned CSR build params ----
    hipMemsetAsync(binmem, 0, 4 * 512 * 4, stream);
    const int nbk_gc = (NE_GC + 4095) / 4096;
    const int nbk_cc = (NE_CC + 4095) / 4096;
    const int nbk_cg = (NE_CG + 4095) / 4096;
    const int nbk_gg = (NE_GG + 4095) / 4096;
    auto mkrel = [&](const int* s, const int* d, int n, int shift, int nbins, int N, int cap,
                     int* deg, int* offg, int* bkt, int* bm, unsigned* stg,
                     int cblk0, int sblk0) {
        RelP r;
        r.src = s; r.dst = d; r.n = n; r.shift = shift; r.nbins = nbins; r.N = N; r.cap = cap;
        r.deg = deg; r.offg = offg; r.bkt = bkt;
        r.bcur = bm; r.stg = stg;
        r.cblk0 = cblk0; r.sblk0 = sblk0;
        return r;
    };
    RelP r0 = mkrel(src_gc, dst_gc, NE_GC, 8, NB_C, NCELL, CAP_GC, deg_gc, off_gc, bkt_gc,
                    binmem + 0 * 512, stg_gc, 0, 0);
    RelP r1 = mkrel(src_cc, dst_cc, NE_CC, 8, NB_C, NCELL, CAP_CC, deg_cc, off_cc, bkt_cc,
                    binmem + 1 * 512, stg_cc, nbk_gc, NB_C);
    RelP r2 = mkrel(src_cg, dst_cg, NE_CG, 4, NB_G, NGENE, CAP_CG, deg_cg, off_cg, bkt_cg,
                    binmem + 2 * 512, stg_cg, nbk_gc + nbk_cc, 2 * NB_C);
    RelP r3 = mkrel(src_gg, dst_gg, NE_GG, 4, NB_G, NGENE, CAP_GG, deg_gg, off_gg, bkt_gg,
                    binmem + 3 * 512, stg_gg, nbk_gc + nbk_cc + nbk_cg, 2 * NB_C + NB_G);
    const int fillBlocks = nbk_gc + nbk_cc + nbk_cg + nbk_gg;
    const int csrBlocks = 2 * NB_C + 2 * NB_G;

    // ---- merged pre-pass: fill | pack (32 blocks) | conv (+ sentinel zeroing) ----
    const int n4c = NCELL * DIM / 4, n4g = NGENE * DIM / 4;
    const int convCB = (n4c + 255) / 256;
    const int convGB = (n4g + 255) / 256;
    const int packBase = fillBlocks;
    const int convBase = fillBlocks + 32;
    const int preBlocks = convBase + convCB + convGB;
    pre_k<<<preBlocks, 256, 0, stream>>>(r0, r1, r2, r3, packBase, convBase, convCB,
                                         h_cell, hcb0, h_gene, hgb0, hcb1, hgb1, n4c, n4g,
                                         W_gc, W_cc, Wp_cell, W_cg, W_gg, Wp_gene);
    bin_csr4_k<<<csrBlocks, 256, 0, stream>>>(r0, r1, r2, r3);

    // ---- two shared layers ----
    const int gatherCB = NCELL / 4;           // 25000
    const int gatherGB = (NGENE + 3) / 4;     // 2000 (scheduled FIRST: longest jobs)
    const int gemmCB = MPC / GBM;             // 782
    const int gemmGB = MPG / GBM;             // 63
    const unsigned short* hc = hcb0;
    const unsigned short* hg = hgb0;
    for (int layer = 0; layer < 2; ++layer) {
        int final_ = (layer == 1);
        gather2_k<<<gatherGB + gatherCB, 256, 0, stream>>>(
            hc, hg,
            off_gc, deg_gc, bkt_gc, off_cc, deg_cc, bkt_cc,
            off_cg, deg_cg, bkt_cg, off_gg, deg_gg, bkt_gg,
            Acat_c, Acat_g, gatherGB);
        gemm2_ln_k<<<gemmCB + gemmGB, 256, 0, stream>>>(
            Acat_c, Acat_g, Wp_cell, Wp_gene, b_cell, b_gene,
            ln_s_cell, ln_b_cell, ln_s_gene, ln_b_gene,
            final_ ? nullptr : hcb1, final_ ? nullptr : hgb1,
            final_ ? out : nullptr, final_ ? out + (size_t)NCELL * DIM : nullptr,
            gemmCB);
        hc = hcb1;
        hg = hgb1;
    }
}

// Round 15
// 463.993 us; speedup vs baseline: 1.1116x; 1.0069x over previous
//
#include <hip/hip_runtime.h>

#define NCELL 100000
#define NGENE 8000
#define DIM   128
#define NE_CG 1500000
#define NE_GC 1500000
#define NE_CC 1000000
#define NE_GG 200000
#define SLOPE 0.05f
#define LN_EPS 1e-5f

typedef __attribute__((ext_vector_type(2))) _Float16 f16x2;
typedef __attribute__((ext_vector_type(8))) _Float16 f16x8;
typedef __attribute__((ext_vector_type(4))) float f32x4;

typedef const __attribute__((address_space(1))) unsigned guint_t;
typedef __attribute__((address_space(3))) unsigned suint_t;

__device__ __forceinline__ unsigned short f2h(float x) {
    return __builtin_bit_cast(unsigned short, (_Float16)x);
}
__device__ __forceinline__ unsigned pack2h(float x, float y) {
    f16x2 h = { (_Float16)x, (_Float16)y };
    return __builtin_bit_cast(unsigned, h);
}
__device__ __forceinline__ f16x2 u2h2(unsigned u) {
    return __builtin_bit_cast(f16x2, u);
}

// ================= binned CSR build, fixed-capacity bins =================
struct RelP {
    const int* src; const int* dst; int n; int shift;
    int nbins; int N; int cap;
    int* deg; int* offg; int* bkt;
    int* bcur; unsigned* stg;
    int cblk0;   // first block id in fill region (pre_k)
    int sblk0;   // first block id in csr grid
};

// ---------------- merged pre-pass: fill (bins) | weight pack | f32->f16 conv ----------
// Conv uses float4 loads (bit-identical values, half the instructions).
// Also zeroes the sentinel row (row N) of all four feature buffers.
__global__ __launch_bounds__(256)
void pre_k(RelP r0, RelP r1, RelP r2, RelP r3, int packBase, int convBase, int convCB,
           const float* __restrict__ h_cell, unsigned short* __restrict__ hcb,
           const float* __restrict__ h_gene, unsigned short* __restrict__ hgb,
           unsigned short* __restrict__ hcb1, unsigned short* __restrict__ hgb1,
           int n4c, int n4g,
           const float* __restrict__ WAc, const float* __restrict__ WBc,
           unsigned short* __restrict__ Wpc,
           const float* __restrict__ WAg, const float* __restrict__ WBg,
           unsigned short* __restrict__ Wpg) {
    __shared__ int cnt[512];
    __shared__ int basem[512];
    int b = blockIdx.x;
    int tid = threadIdx.x;

    if (b >= convBase) {
        // ---- f32 -> f16 conversion (cell then gene), float4-wide ----
        int cb = b - convBase;
        const float* in; unsigned short* out; int i, n4;
        if (cb < convCB) { in = h_cell; out = hcb; n4 = n4c; i = cb * 256 + tid; }
        else             { in = h_gene; out = hgb; n4 = n4g; i = (cb - convCB) * 256 + tid; }
        if (i < n4) {
            float4 v = ((const float4*)in)[i];
            ((uint2*)out)[i] = make_uint2(pack2h(v.x, v.y), pack2h(v.z, v.w));
        }
        if (cb == 0) {
            // zero the sentinel rows (row NCELL / NGENE) of all four feature buffers
            int n2c = n4c * 2, n2g = n4g * 2;
            if (tid < 64)       ((unsigned*)hcb )[n2c + tid]       = 0;
            else if (tid < 128) ((unsigned*)hcb1)[n2c + tid - 64]  = 0;
            else if (tid < 192) ((unsigned*)hgb )[n2g + tid - 128] = 0;
            else                ((unsigned*)hgb1)[n2g + tid - 192] = 0;
        }
        return;
    }
    if (b >= packBase) {
        // ---- weight pack: [W1;W2] -> MFMA B-frag layout (f16), 4 sub-blocks/block ----
        int sub = (b - packBase) * 4 + (tid >> 6);   // 0..127 (= original blockIdx)
        int lane = tid & 63;
        const float *WA, *WB; unsigned short* Wp; int bb;
        if (sub < 64) { WA = WAc; WB = WBc; Wp = Wpc; bb = sub; }
        else          { WA = WAg; WB = WBg; Wp = Wpg; bb = sub - 64; }
        int t = bb >> 3, cc = bb & 7;
        int n = t * 16 + (lane & 15);
        int k0 = cc * 32 + (lane >> 4) * 8;
        #pragma unroll
        for (int j = 0; j < 8; ++j) {
            int k = k0 + j;
            float x = (k < 128) ? WA[k * 128 + n] : WB[(k - 128) * 128 + n];
            Wp[((size_t)(bb * 64 + lane)) * 8 + j] = f2h(x);
        }
        return;
    }

    // ---- bin fill (fixed-cap bins) ----
    RelP R = (b >= r3.cblk0) ? r3 : (b >= r2.cblk0) ? r2 : (b >= r1.cblk0) ? r1 : r0;
    int lb = b - R.cblk0;
    cnt[tid] = 0; cnt[tid + 256] = 0;
    __syncthreads();
    int base = lb * 4096;
    int bins[16]; int ranks[16]; unsigned pk[16];
    #pragma unroll
    for (int it = 0; it < 16; ++it) {
        int i = base + it * 256 + tid;
        bins[it] = -1;
        if (i < R.n) {
            int d = R.dst[i];
            int bn = d >> R.shift;
            int dl = d & ((1 << R.shift) - 1);
            bins[it] = bn;
            pk[it] = (unsigned)R.src[i] | ((unsigned)dl << 20);
            ranks[it] = atomicAdd(&cnt[bn], 1);
        }
    }
    __syncthreads();
    if (cnt[tid])       basem[tid]       = atomicAdd(&R.bcur[tid],       cnt[tid]);
    if (cnt[tid + 256]) basem[tid + 256] = atomicAdd(&R.bcur[tid + 256], cnt[tid + 256]);
    __syncthreads();
    #pragma unroll
    for (int it = 0; it < 16; ++it)
        if (bins[it] >= 0) {
            int r = basem[bins[it]] + ranks[it];
            if (r >= R.cap) r = R.cap - 1;           // paranoia clamp (stays in own bin)
            R.stg[(size_t)bins[it] * R.cap + r] = pk[it];
        }
}

// counting-sort per bin; scatter goes to LDS, final global write is coalesced.
__global__ __launch_bounds__(256)
void bin_csr4_k(RelP r0, RelP r1, RelP r2, RelP r3) {
    int b = blockIdx.x;
    RelP R = (b >= r3.sblk0) ? r3 : (b >= r2.sblk0) ? r2 : (b >= r1.sblk0) ? r1 : r0;
    int lb = b - R.sblk0;
    int tid = threadIdx.x;
    int ebase = lb * R.cap;
    int cnt = R.bcur[lb]; if (cnt > R.cap) cnt = R.cap;
    __shared__ int degm[256];
    __shared__ int sc[256];
    __shared__ int cur[256];
    __shared__ int bktl[4352];   // >= max cap (CAP_GC)
    degm[tid] = 0;
    __syncthreads();
    for (int i = tid; i < cnt; i += 256)
        atomicAdd(&degm[(R.stg[ebase + i] >> 20) & 255], 1);
    __syncthreads();
    int x = degm[tid];
    sc[tid] = x;
    __syncthreads();
    for (int ofs = 1; ofs < 256; ofs <<= 1) {
        int t = (tid >= ofs) ? sc[tid - ofs] : 0;
        __syncthreads();
        sc[tid] += t;
        __syncthreads();
    }
    int excl = sc[tid] - x;
    cur[tid] = excl;
    int node = (lb << R.shift) + tid;
    if (tid < (1 << R.shift) && node < R.N) { R.deg[node] = x; R.offg[node] = ebase + excl; }
    __syncthreads();
    for (int i = tid; i < cnt; i += 256) {
        unsigned p = R.stg[ebase + i];
        int dl = (p >> 20) & 255;
        int r = atomicAdd(&cur[dl], 1);
        bktl[r] = (int)(p & 0xFFFFFu);
    }
    __syncthreads();
    for (int i = tid; i < cnt; i += 256)
        R.bkt[ebase + i] = bktl[i];
}

// ---------------- fused vectorized gather: sentinel-row unconditional f16 pk-add ------
// r10 configuration (verified 117 us): MERGED A/B loop (max MLP), sentinel zero-row
// unconditional loads/adds, wave-uniform t-skip, gene blocks FIRST. Untouched.
__global__ __launch_bounds__(256)
void gather2_k(const unsigned short* __restrict__ hc, const unsigned short* __restrict__ hg,
               const int* __restrict__ off_gc, const int* __restrict__ deg_gc, const int* __restrict__ bkt_gc,
               const int* __restrict__ off_cc, const int* __restrict__ deg_cc, const int* __restrict__ bkt_cc,
               const int* __restrict__ off_cg, const int* __restrict__ deg_cg, const int* __restrict__ bkt_cg,
               const int* __restrict__ off_gg, const int* __restrict__ deg_gg, const int* __restrict__ bkt_gg,
               unsigned short* __restrict__ Acat_c, unsigned short* __restrict__ Acat_g,
               int geneBlocks) {
    int wave = threadIdx.x >> 6, lane = threadIdx.x & 63;
    int g = lane >> 4, c = lane & 15;
    const unsigned short *hA, *hB;
    const int *offA, *degA, *bktA, *offB, *degB, *bktB;
    unsigned short* Aout; int node, N; int sentA, sentB;
    if ((int)blockIdx.x < geneBlocks) {
        node = blockIdx.x * 4 + wave; N = NGENE;
        hA = hc; offA = off_cg; degA = deg_cg; bktA = bkt_cg; sentA = NCELL;
        hB = hg; offB = off_gg; degB = deg_gg; bktB = bkt_gg; sentB = NGENE;
        Aout = Acat_g;
    } else {
        node = (blockIdx.x - geneBlocks) * 4 + wave; N = NCELL;
        hA = hg; offA = off_gc; degA = deg_gc; bktA = bkt_gc; sentA = NGENE;
        hB = hc; offB = off_cc; degB = deg_cc; bktB = bkt_cc; sentB = NCELL;
        Aout = Acat_c;
    }
    if (node >= N) return;

    int nA = degA[node], sA = offA[node];
    int nB = degB[node], sB = offB[node];

    f16x2 aA[4], aB[4];
    #pragma unroll
    for (int i = 0; i < 4; ++i) { aA[i] = (f16x2)(_Float16)0; aB[i] = (f16x2)(_Float16)0; }
    int mx = (nA > nB) ? nA : nB;

    for (int j0 = 0; j0 < mx; j0 += 32) {
        int l32 = lane & 31;
        int jj = j0 + l32;
        int iv;
        if (lane < 32) { iv = sentA; if (jj < nA) iv = bktA[sA + jj]; }
        else           { iv = sentB; if (jj < nB) iv = bktB[sB + jj]; }
        int mxb = mx - j0;            // wave-uniform remaining edge count
        #pragma unroll
        for (int t = 0; t < 8; ++t) {
            if (t * 4 < mxb) {        // wave-uniform skip: s_cbranch, full exec inside
                int j = t * 4 + g;
                int sidxA = __shfl(iv, j);
                int sidxB = __shfl(iv, 32 + j);
                uint4 vA = *(const uint4*)(hA + (size_t)sidxA * DIM + c * 8);
                uint4 vB = *(const uint4*)(hB + (size_t)sidxB * DIM + c * 8);
                aA[0] += u2h2(vA.x); aA[1] += u2h2(vA.y);
                aA[2] += u2h2(vA.z); aA[3] += u2h2(vA.w);
                aB[0] += u2h2(vB.x); aB[1] += u2h2(vB.y);
                aB[2] += u2h2(vB.z); aB[3] += u2h2(vB.w);
            }
        }
    }

    // widen to f32, cross-group reduce, normalize, pack
    float fA[8], fB[8];
    #pragma unroll
    for (int i = 0; i < 4; ++i) {
        fA[2 * i]     = (float)aA[i][0]; fA[2 * i + 1] = (float)aA[i][1];
        fB[2 * i]     = (float)aB[i][0]; fB[2 * i + 1] = (float)aB[i][1];
    }
    #pragma unroll
    for (int i = 0; i < 8; ++i) {
        fA[i] += __shfl_xor(fA[i], 16); fA[i] += __shfl_xor(fA[i], 32);
        fB[i] += __shfl_xor(fB[i], 16); fB[i] += __shfl_xor(fB[i], 32);
    }
    float invA = 1.0f / fmaxf((float)nA, 1.0f);
    float invB = 1.0f / fmaxf((float)nB, 1.0f);
    uint4* outrow = (uint4*)(Aout + (size_t)node * 256);
    if (g == 0) {
        outrow[c] = make_uint4(pack2h(fA[0] * invA, fA[1] * invA), pack2h(fA[2] * invA, fA[3] * invA),
                               pack2h(fA[4] * invA, fA[5] * invA), pack2h(fA[6] * invA, fA[7] * invA));
    } else if (g == 1) {
        outrow[16 + c] = make_uint4(pack2h(fB[0] * invB, fB[1] * invB), pack2h(fB[2] * invB, fB[3] * invB),
                                    pack2h(fB[4] * invB, fB[5] * invB), pack2h(fB[6] * invB, fB[7] * invB));
    }
}

// ---------------- fused MFMA GEMM (f16) + bias + LeakyReLU + LN (cell & gene) ------------
// r15: staging now uses global_load_lds (direct HBM/L2 -> LDS, no VGPR round-trip).
// Per k-iteration a wave covers one fragment-line: uniform LDS base fl*1024 + lane*16,
// per-lane global source f*1024 + lane*16 — exact wave-uniform-dest contract.
// Byte mapping identical to r14 -> bit-identical results. First half skips the
// leading barrier (nothing has read LDS yet).
#define GBM 128
__global__ __launch_bounds__(256, 3)
void gemm2_ln_k(const unsigned short* __restrict__ Acat_c, const unsigned short* __restrict__ Acat_g,
                const unsigned short* __restrict__ Wp_c, const unsigned short* __restrict__ Wp_g,
                const float* __restrict__ bias_c, const float* __restrict__ bias_g,
                const float* __restrict__ ls_c, const float* __restrict__ lb_c,
                const float* __restrict__ ls_g, const float* __restrict__ lb_g,
                unsigned short* __restrict__ outh_c, unsigned short* __restrict__ outh_g,
                float* __restrict__ outf_c, float* __restrict__ outf_g,
                int cellBlocks) {
    const unsigned short *A, *Wp; const float *bias, *lns, *lnb;
    unsigned short* outh; float* outf; int M, mb;
    if ((int)blockIdx.x < cellBlocks) {
        A = Acat_c; Wp = Wp_c; bias = bias_c; lns = ls_c; lnb = lb_c;
        outh = outh_c; outf = outf_c; M = NCELL; mb = blockIdx.x;
    } else {
        A = Acat_g; Wp = Wp_g; bias = bias_g; lns = ls_g; lnb = lb_g;
        outh = outh_g; outf = outf_g; M = NGENE; mb = blockIdx.x - cellBlocks;
    }
    __shared__ unsigned short Ws[16384];   // 32 KB: one half (32 B-fragments of 1KB)
    int tid = threadIdx.x;
    int wave = tid >> 6, lane = tid & 63;
    int col0 = lane & 15;
    int kq = lane >> 4;
    int m_base = mb * GBM + wave * 32;

    f32x4 acc[2][8];
    #pragma unroll
    for (int mt = 0; mt < 2; ++mt)
        #pragma unroll
        for (int t = 0; t < 8; ++t) acc[mt][t] = (f32x4){0.f, 0.f, 0.f, 0.f};

    const unsigned short* Ar0 = A + (size_t)(m_base + col0) * 256 + kq * 8;
    const unsigned short* Ar1 = Ar0 + 16 * 256;

    #pragma unroll
    for (int cch = 0; cch < 2; ++cch) {
        // stage fragments f = t*8 + cch*4 + cc2 (t=0..7, cc2=0..3) -> LDS slot fl = t*4+cc2
        if (cch) __syncthreads();            // protect LDS from overwrite (not needed 1st)
        #pragma unroll
        for (int k = 0; k < 8; ++k) {
            int fl = k * 4 + wave;           // 0..31 across 4 waves x 8 k
            int f = (fl >> 2) * 8 + cch * 4 + (fl & 3);
            __builtin_amdgcn_global_load_lds(
                (guint_t*)((const char*)Wp + (size_t)f * 1024 + lane * 16),
                (suint_t*)((char*)Ws + fl * 1024),
                16, 0, 0);
        }
        __syncthreads();
        #pragma unroll
        for (int cc2 = 0; cc2 < 4; ++cc2) {
            int cc = cch * 4 + cc2;
            f16x8 a0 = *(const f16x8*)(Ar0 + cc * 32);
            f16x8 a1 = *(const f16x8*)(Ar1 + cc * 32);
            #pragma unroll
            for (int t = 0; t < 8; ++t) {
                f16x8 b = *(const f16x8*)(Ws + ((t * 4 + cc2) * 64 + lane) * 8);
                acc[0][t] = __builtin_amdgcn_mfma_f32_16x16x32_f16(a0, b, acc[0][t], 0, 0, 0);
                acc[1][t] = __builtin_amdgcn_mfma_f32_16x16x32_f16(a1, b, acc[1][t], 0, 0, 0);
            }
        }
    }

    float bias_r[8], s_r[8], b_r[8];
    #pragma unroll
    for (int t = 0; t < 8; ++t) {
        int col = t * 16 + col0;
        bias_r[t] = bias[col]; s_r[t] = lns[col]; b_r[t] = lnb[col];
    }
    #pragma unroll
    for (int mt = 0; mt < 2; ++mt) {
        #pragma unroll
        for (int r = 0; r < 4; ++r) {
            int row = m_base + mt * 16 + kq * 4 + r;
            float v[8]; float sum = 0.f, sq = 0.f;
            #pragma unroll
            for (int t = 0; t < 8; ++t) {
                float x = acc[mt][t][r] + bias_r[t];
                x = (x >= 0.f) ? x : SLOPE * x;
                v[t] = x; sum += x; sq += x * x;
            }
            #pragma unroll
            for (int ofs = 1; ofs <= 8; ofs <<= 1) {
                sum += __shfl_xor(sum, ofs);
                sq  += __shfl_xor(sq, ofs);
            }
            float mu = sum * (1.0f / 128.0f);
            float var = sq * (1.0f / 128.0f) - mu * mu;
            float rstd = rsqrtf(var + LN_EPS);
            if (row < M) {
                if (outh) {
                    #pragma unroll
                    for (int t = 0; t < 8; ++t)
                        outh[(size_t)row * 128 + t * 16 + col0] =
                            f2h((v[t] - mu) * rstd * s_r[t] + b_r[t]);
                } else {
                    #pragma unroll
                    for (int t = 0; t < 8; ++t)
                        outf[(size_t)row * 128 + t * 16 + col0] =
                            (v[t] - mu) * rstd * s_r[t] + b_r[t];
                }
            }
        }
    }
}

extern "C" void kernel_launch(void* const* d_in, const int* in_sizes, int n_in,
                              void* d_out, int out_size, void* d_ws, size_t ws_size,
                              hipStream_t stream) {
    const float* h_cell = (const float*)d_in[0];
    const float* h_gene = (const float*)d_in[1];
    const int* src_cg = (const int*)d_in[2];
    const int* dst_cg = (const int*)d_in[3];
    const int* src_gc = (const int*)d_in[4];
    const int* dst_gc = (const int*)d_in[5];
    const int* src_cc = (const int*)d_in[6];
    const int* dst_cc = (const int*)d_in[7];
    const int* src_gg = (const int*)d_in[8];
    const int* dst_gg = (const int*)d_in[9];
    const float* W_cg = (const float*)d_in[10];
    const float* W_gc = (const float*)d_in[11];
    const float* W_cc = (const float*)d_in[12];
    const float* W_gg = (const float*)d_in[13];
    const float* b_cell = (const float*)d_in[14];
    const float* b_gene = (const float*)d_in[15];
    const float* ln_s_cell = (const float*)d_in[16];
    const float* ln_b_cell = (const float*)d_in[17];
    const float* ln_s_gene = (const float*)d_in[18];
    const float* ln_b_gene = (const float*)d_in[19];
    float* out = (float*)d_out;

    const int MPC = ((NCELL + GBM - 1) / GBM) * GBM;
    const int MPG = ((NGENE + GBM - 1) / GBM) * GBM;
    const int NB_C = (NCELL + 255) / 256;   // 391 bins (shift 8)
    const int NB_G = (NGENE + 15) / 16;     // 500 bins (shift 4)
    // fixed bin capacities: mean + >8 sigma (Poisson)
    const int CAP_GC = 4352;   // mean 3836
    const int CAP_CC = 3072;   // mean 2558
    const int CAP_CG = 3584;   // mean 3000
    const int CAP_GG = 768;    // mean 400

    char* wsb = (char*)d_ws;
    size_t off = 0;
    auto alloc = [&](size_t bytes) -> char* {
        char* p = wsb + off;
        off = (off + bytes + 255) & ~(size_t)255;
        return p;
    };
    unsigned short* Acat_c = (unsigned short*)alloc((size_t)MPC * 256 * 2);
    unsigned short* Acat_g = (unsigned short*)alloc((size_t)MPG * 256 * 2);
    // feature buffers carry one extra SENTINEL row (row N, zeroed in pre_k)
    unsigned short* hcb0 = (unsigned short*)alloc((size_t)(NCELL + 1) * DIM * 2);
    unsigned short* hgb0 = (unsigned short*)alloc((size_t)(NGENE + 1) * DIM * 2);
    unsigned short* hcb1 = (unsigned short*)alloc((size_t)(NCELL + 1) * DIM * 2);
    unsigned short* hgb1 = (unsigned short*)alloc((size_t)(NGENE + 1) * DIM * 2);
    unsigned short* Wp_cell = (unsigned short*)alloc(65536);
    unsigned short* Wp_gene = (unsigned short*)alloc(65536);
    int ndeg = 2 * NCELL + 2 * NGENE;
    int* degs = (int*)alloc((size_t)ndeg * 4);
    int* deg_gc = degs;
    int* deg_cc = degs + NCELL;
    int* deg_cg = degs + 2 * NCELL;
    int* deg_gg = degs + 2 * NCELL + NGENE;
    int* offs = (int*)alloc((size_t)ndeg * 4);
    int* off_gc = offs;
    int* off_cc = offs + NCELL;
    int* off_cg = offs + 2 * NCELL;
    int* off_gg = offs + 2 * NCELL + NGENE;
    int* bkt_gc = (int*)alloc((size_t)NB_C * CAP_GC * 4);
    int* bkt_cc = (int*)alloc((size_t)NB_C * CAP_CC * 4);
    int* bkt_cg = (int*)alloc((size_t)NB_G * CAP_CG * 4);
    int* bkt_gg = (int*)alloc((size_t)NB_G * CAP_GG * 4);
    unsigned* stg_gc = (unsigned*)alloc((size_t)NB_C * CAP_GC * 4);
    unsigned* stg_cc = (unsigned*)alloc((size_t)NB_C * CAP_CC * 4);
    unsigned* stg_cg = (unsigned*)alloc((size_t)NB_G * CAP_CG * 4);
    unsigned* stg_gg = (unsigned*)alloc((size_t)NB_G * CAP_GG * 4);
    int* binmem = (int*)alloc(4 * 512 * 4);

    // ---- binned CSR build params ----
    hipMemsetAsync(binmem, 0, 4 * 512 * 4, stream);
    const int nbk_gc = (NE_GC + 4095) / 4096;
    const int nbk_cc = (NE_CC + 4095) / 4096;
    const int nbk_cg = (NE_CG + 4095) / 4096;
    const int nbk_gg = (NE_GG + 4095) / 4096;
    auto mkrel = [&](const int* s, const int* d, int n, int shift, int nbins, int N, int cap,
                     int* deg, int* offg, int* bkt, int* bm, unsigned* stg,
                     int cblk0, int sblk0) {
        RelP r;
        r.src = s; r.dst = d; r.n = n; r.shift = shift; r.nbins = nbins; r.N = N; r.cap = cap;
        r.deg = deg; r.offg = offg; r.bkt = bkt;
        r.bcur = bm; r.stg = stg;
        r.cblk0 = cblk0; r.sblk0 = sblk0;
        return r;
    };
    RelP r0 = mkrel(src_gc, dst_gc, NE_GC, 8, NB_C, NCELL, CAP_GC, deg_gc, off_gc, bkt_gc,
                    binmem + 0 * 512, stg_gc, 0, 0);
    RelP r1 = mkrel(src_cc, dst_cc, NE_CC, 8, NB_C, NCELL, CAP_CC, deg_cc, off_cc, bkt_cc,
                    binmem + 1 * 512, stg_cc, nbk_gc, NB_C);
    RelP r2 = mkrel(src_cg, dst_cg, NE_CG, 4, NB_G, NGENE, CAP_CG, deg_cg, off_cg, bkt_cg,
                    binmem + 2 * 512, stg_cg, nbk_gc + nbk_cc, 2 * NB_C);
    RelP r3 = mkrel(src_gg, dst_gg, NE_GG, 4, NB_G, NGENE, CAP_GG, deg_gg, off_gg, bkt_gg,
                    binmem + 3 * 512, stg_gg, nbk_gc + nbk_cc + nbk_cg, 2 * NB_C + NB_G);
    const int fillBlocks = nbk_gc + nbk_cc + nbk_cg + nbk_gg;
    const int csrBlocks = 2 * NB_C + 2 * NB_G;

    // ---- merged pre-pass: fill | pack (32 blocks) | conv (+ sentinel zeroing) ----
    const int n4c = NCELL * DIM / 4, n4g = NGENE * DIM / 4;
    const int convCB = (n4c + 255) / 256;
    const int convGB = (n4g + 255) / 256;
    const int packBase = fillBlocks;
    const int convBase = fillBlocks + 32;
    const int preBlocks = convBase + convCB + convGB;
    pre_k<<<preBlocks, 256, 0, stream>>>(r0, r1, r2, r3, packBase, convBase, convCB,
                                         h_cell, hcb0, h_gene, hgb0, hcb1, hgb1, n4c, n4g,
                                         W_gc, W_cc, Wp_cell, W_cg, W_gg, Wp_gene);
    bin_csr4_k<<<csrBlocks, 256, 0, stream>>>(r0, r1, r2, r3);

    // ---- two shared layers ----
    const int gatherCB = NCELL / 4;           // 25000
    const int gatherGB = (NGENE + 3) / 4;     // 2000 (scheduled FIRST: longest jobs)
    const int gemmCB = MPC / GBM;             // 782
    const int gemmGB = MPG / GBM;             // 63
    const unsigned short* hc = hcb0;
    const unsigned short* hg = hgb0;
    for (int layer = 0; layer < 2; ++layer) {
        int final_ = (layer == 1);
        gather2_k<<<gatherGB + gatherCB, 256, 0, stream>>>(
            hc, hg,
            off_gc, deg_gc, bkt_gc, off_cc, deg_cc, bkt_cc,
            off_cg, deg_cg, bkt_cg, off_gg, deg_gg, bkt_gg,
            Acat_c, Acat_g, gatherGB);
        gemm2_ln_k<<<gemmCB + gemmGB, 256, 0, stream>>>(
            Acat_c, Acat_g, Wp_cell, Wp_gene, b_cell, b_gene,
            ln_s_cell, ln_b_cell, ln_s_gene, ln_b_gene,
            final_ ? nullptr : hcb1, final_ ? nullptr : hgb1,
            final_ ? out : nullptr, final_ ? out + (size_t)NCELL * DIM : nullptr,
            gemmCB);
        hc = hcb1;
        hg = hgb1;
    }
}